// Round 1
// baseline (536.393 us; speedup 1.0000x reference)
//
#include <hip/hip_runtime.h>
#include <math.h>

#define NB 1024
#define NP 256
#define FIN 8
#define NH 16
#define NK 8

__device__ __forceinline__ float elu_f(float v) {
    return v > 0.f ? v : (__expf(v) - 1.f);
}

__global__ __launch_bounds__(256, 4) void edgenet_kernel(
    const float* __restrict__ gx,
    const float* __restrict__ gW1, const float* __restrict__ gW2, const float* __restrict__ gb2,
    const float* __restrict__ gW3, const float* __restrict__ gb3,
    const float* __restrict__ gWe, const float* __restrict__ gbe,
    const float* __restrict__ gWo1, const float* __restrict__ gbo1,
    const float* __restrict__ gWo2, const float* __restrict__ gbo2,
    float* __restrict__ gout)
{
    const int b = blockIdx.x;
    const int t = threadIdx.x;

    __shared__ __align__(16) float sW1[NH * FIN];
    __shared__ __align__(16) float sW2[NH * NH];
    __shared__ __align__(16) float sW3[NH * NH];
    __shared__ __align__(16) float sWb[NH * NH];   // We[:,16:32]
    __shared__ __align__(16) float sWc[NH * NH];   // We[:,0:16] - We[:,16:32]
    __shared__ __align__(16) float sb2[NH], sb3[NH], sbe[NH];
    __shared__ __align__(16) float sWo1[8 * NH];
    __shared__ __align__(16) float sbo1[8], sWo2[8], sbo2[1];
    // h rows: [16 features][1 sq][3 pad] -> 20 floats = 80 B (16B aligned, bank-spread)
    __shared__ __align__(16) float sh[NP][20];

    // ---- cooperative weight staging ----
    if (t < NH * FIN) sW1[t] = gW1[t];
    sW2[t] = gW2[t];
    sW3[t] = gW3[t];
    {
        int o = t >> 4, i = t & 15;
        float a = gWe[o * 32 + i];
        float c = gWe[o * 32 + 16 + i];
        sWb[t] = c;
        sWc[t] = a - c;
    }
    if (t < NH) { sb2[t] = gb2[t]; sb3[t] = gb3[t]; sbe[t] = gbe[t]; }
    if (t < 8 * NH) sWo1[t] = gWo1[t];
    if (t < 8) { sbo1[t] = gbo1[t]; sWo2[t] = gWo2[t]; }
    if (t == 0) sbo2[0] = gbo2[0];

    // ---- load this thread's particle (8 floats, 2x float4, coalesced) ----
    float xin[FIN];
    {
        const float4* xr = reinterpret_cast<const float4*>(gx + (size_t)b * (NP * FIN) + t * FIN);
        float4 v0 = xr[0], v1 = xr[1];
        xin[0] = v0.x; xin[1] = v0.y; xin[2] = v0.z; xin[3] = v0.w;
        xin[4] = v1.x; xin[5] = v1.y; xin[6] = v1.z; xin[7] = v1.w;
    }
    __syncthreads();

    // ---- encoder MLP: 8 -> 16 -> 16 -> 16, ELU ----
    float l1[NH], l2[NH], hp[NH];
    #pragma unroll
    for (int o = 0; o < NH; ++o) {
        float s = 0.f;
        #pragma unroll
        for (int i = 0; i < FIN; ++i) s = fmaf(sW1[o * FIN + i], xin[i], s);
        l1[o] = elu_f(s);
    }
    #pragma unroll
    for (int o = 0; o < NH; ++o) {
        float s = sb2[o];
        #pragma unroll
        for (int i = 0; i < NH; ++i) s = fmaf(sW2[o * NH + i], l1[i], s);
        l2[o] = elu_f(s);
    }
    #pragma unroll
    for (int o = 0; o < NH; ++o) {
        float s = sb3[o];
        #pragma unroll
        for (int i = 0; i < NH; ++i) s = fmaf(sW3[o * NH + i], l2[i], s);
        hp[o] = elu_f(s);
    }

    float sqp = 0.f;
    #pragma unroll
    for (int i = 0; i < NH; ++i) sqp = fmaf(hp[i], hp[i], sqp);

    #pragma unroll
    for (int i = 0; i < NH; ++i) sh[t][i] = hp[i];
    sh[t][NH] = sqp;
    __syncthreads();

    // ---- kNN: top-8 smallest distances, tie -> smaller index ----
    // packed key: high 24 bits of float dist | 8-bit index. min/max sorted insert.
    float bk[NK];
    #pragma unroll
    for (int s = 0; s < NK; ++s) bk[s] = __uint_as_float(0x7F7FFFFFu);

    for (int j = 0; j < NP; ++j) {
        const float4* row = reinterpret_cast<const float4*>(&sh[j][0]);
        float4 r0 = row[0], r1 = row[1], r2 = row[2], r3 = row[3];
        float sqj = sh[j][NH];
        float dot = 0.f;
        dot = fmaf(hp[0],  r0.x, dot); dot = fmaf(hp[1],  r0.y, dot);
        dot = fmaf(hp[2],  r0.z, dot); dot = fmaf(hp[3],  r0.w, dot);
        dot = fmaf(hp[4],  r1.x, dot); dot = fmaf(hp[5],  r1.y, dot);
        dot = fmaf(hp[6],  r1.z, dot); dot = fmaf(hp[7],  r1.w, dot);
        dot = fmaf(hp[8],  r2.x, dot); dot = fmaf(hp[9],  r2.y, dot);
        dot = fmaf(hp[10], r2.z, dot); dot = fmaf(hp[11], r2.w, dot);
        dot = fmaf(hp[12], r3.x, dot); dot = fmaf(hp[13], r3.y, dot);
        dot = fmaf(hp[14], r3.z, dot); dot = fmaf(hp[15], r3.w, dot);
        float d = fmaf(-2.f, dot, sqp + sqj);
        d = fmaxf(d, 0.f);
        float kf = __uint_as_float((__float_as_uint(d) & 0xFFFFFF00u) | (unsigned)j);
        #pragma unroll
        for (int s = 0; s < NK; ++s) {
            float lo = fminf(bk[s], kf);
            kf = fmaxf(bk[s], kf);
            bk[s] = lo;
        }
    }

    // ---- edge MLP + max aggregation ----
    // m[o] = ELU( be[o] + (We_a - We_b)[o]·xi + We_b[o]·xj )
    float base_[NH];
    #pragma unroll
    for (int o = 0; o < NH; ++o) {
        float s = sbe[o];
        #pragma unroll
        for (int i = 0; i < NH; ++i) s = fmaf(sWc[o * NH + i], hp[i], s);
        base_[o] = s;
    }

    float nodemax[NH];
    #pragma unroll
    for (int o = 0; o < NH; ++o) nodemax[o] = -INFINITY;

    #pragma unroll
    for (int k = 0; k < NK; ++k) {
        int j = (int)(__float_as_uint(bk[k]) & 0xFFu);
        const float4* row = reinterpret_cast<const float4*>(&sh[j][0]);
        float4 r0 = row[0], r1 = row[1], r2 = row[2], r3 = row[3];
        float hj[NH];
        hj[0]  = r0.x; hj[1]  = r0.y; hj[2]  = r0.z; hj[3]  = r0.w;
        hj[4]  = r1.x; hj[5]  = r1.y; hj[6]  = r1.z; hj[7]  = r1.w;
        hj[8]  = r2.x; hj[9]  = r2.y; hj[10] = r2.z; hj[11] = r2.w;
        hj[12] = r3.x; hj[13] = r3.y; hj[14] = r3.z; hj[15] = r3.w;
        #pragma unroll
        for (int o = 0; o < NH; ++o) {
            float s = base_[o];
            #pragma unroll
            for (int i = 0; i < NH; ++i) s = fmaf(sWb[o * NH + i], hj[i], s);
            s = elu_f(s);
            nodemax[o] = fmaxf(nodemax[o], s);
        }
    }

    // ---- mean-pool over particles (LDS tree reduce, reuse sh) ----
    __syncthreads();   // everyone done gathering from sh
    #pragma unroll
    for (int i = 0; i < NH; ++i) sh[t][i] = nodemax[i];
    __syncthreads();
    for (int s = 128; s > 0; s >>= 1) {
        if (t < s) {
            #pragma unroll
            for (int i = 0; i < NH; ++i) sh[t][i] += sh[t + s][i];
        }
        __syncthreads();
    }

    // ---- head MLP + sigmoid (thread 0) ----
    if (t == 0) {
        float o1[8];
        #pragma unroll
        for (int o = 0; o < 8; ++o) {
            float s = sbo1[o];
            #pragma unroll
            for (int i = 0; i < NH; ++i) s = fmaf(sWo1[o * NH + i], sh[0][i] * (1.f / NP), s);
            o1[o] = elu_f(s);
        }
        float o2 = sbo2[0];
        #pragma unroll
        for (int i = 0; i < 8; ++i) o2 = fmaf(sWo2[i], o1[i], o2);
        gout[b] = 1.f / (1.f + expf(-o2));
    }
}

extern "C" void kernel_launch(void* const* d_in, const int* in_sizes, int n_in,
                              void* d_out, int out_size, void* d_ws, size_t ws_size,
                              hipStream_t stream) {
    const float* x   = (const float*)d_in[0];
    const float* W1  = (const float*)d_in[1];
    const float* W2  = (const float*)d_in[2];
    const float* b2  = (const float*)d_in[3];
    const float* W3  = (const float*)d_in[4];
    const float* b3  = (const float*)d_in[5];
    const float* We  = (const float*)d_in[6];
    const float* be  = (const float*)d_in[7];
    const float* Wo1 = (const float*)d_in[8];
    const float* bo1 = (const float*)d_in[9];
    const float* Wo2 = (const float*)d_in[10];
    const float* bo2 = (const float*)d_in[11];
    float* out = (float*)d_out;

    hipLaunchKernelGGL(edgenet_kernel, dim3(NB), dim3(NP), 0, stream,
                       x, W1, W2, b2, W3, b3, We, be, Wo1, bo1, Wo2, bo2, out);
}

// Round 2
// 524.085 us; speedup vs baseline: 1.0235x; 1.0235x over previous
//
#include <hip/hip_runtime.h>
#include <math.h>

#define NB 1024
#define NP 256
#define FIN 8
#define NH 16
#define NK 8

__device__ __forceinline__ float elu_f(float v) {
    return v > 0.f ? v : (__expf(v) - 1.f);
}

__global__ __launch_bounds__(256)
__attribute__((amdgpu_waves_per_eu(4, 4)))
void edgenet_kernel(
    const float* __restrict__ gx,
    const float* __restrict__ gW1, const float* __restrict__ gW2, const float* __restrict__ gb2,
    const float* __restrict__ gW3, const float* __restrict__ gb3,
    const float* __restrict__ gWe, const float* __restrict__ gbe,
    const float* __restrict__ gWo1, const float* __restrict__ gbo1,
    const float* __restrict__ gWo2, const float* __restrict__ gbo2,
    float* __restrict__ gout)
{
    const int b = blockIdx.x;
    const int t = threadIdx.x;

    __shared__ __align__(16) float sW1[NH * FIN];
    __shared__ __align__(16) float sW2[NH * NH];
    __shared__ __align__(16) float sW3[NH * NH];
    __shared__ __align__(16) float sWb[NH * NH];   // We[:,16:32]
    __shared__ __align__(16) float sWc[NH * NH];   // We[:,0:16] - We[:,16:32]
    __shared__ __align__(16) float sb2[NH], sb3[NH], sbe[NH];
    __shared__ __align__(16) float sWo1[8 * NH];
    __shared__ __align__(16) float sbo1[8], sWo2[8], sbo2[1];
    // h rows: [16 features][1 sq][3 pad] -> 20 floats = 80 B (16B aligned)
    __shared__ __align__(16) float sh[NP][20];

    // ---- cooperative weight staging ----
    if (t < NH * FIN) sW1[t] = gW1[t];
    sW2[t] = gW2[t];
    sW3[t] = gW3[t];
    {
        int o = t >> 4, i = t & 15;
        float a = gWe[o * 32 + i];
        float c = gWe[o * 32 + 16 + i];
        sWb[t] = c;
        sWc[t] = a - c;
    }
    if (t < NH) { sb2[t] = gb2[t]; sb3[t] = gb3[t]; sbe[t] = gbe[t]; }
    if (t < 8 * NH) sWo1[t] = gWo1[t];
    if (t < 8) { sbo1[t] = gbo1[t]; sWo2[t] = gWo2[t]; }
    if (t == 0) sbo2[0] = gbo2[0];

    // ---- load this thread's particle (8 floats, 2x float4, coalesced) ----
    float xin[FIN];
    {
        const float4* xr = reinterpret_cast<const float4*>(gx + (size_t)b * (NP * FIN) + t * FIN);
        float4 v0 = xr[0], v1 = xr[1];
        xin[0] = v0.x; xin[1] = v0.y; xin[2] = v0.z; xin[3] = v0.w;
        xin[4] = v1.x; xin[5] = v1.y; xin[6] = v1.z; xin[7] = v1.w;
    }
    __syncthreads();

    // ---- encoder MLP: 8 -> 16 -> 16 -> 16, ELU ----
    float l1[NH], l2[NH], hp[NH];
    #pragma unroll
    for (int o = 0; o < NH; ++o) {
        float s = 0.f;
        #pragma unroll
        for (int i = 0; i < FIN; ++i) s = fmaf(sW1[o * FIN + i], xin[i], s);
        l1[o] = elu_f(s);
    }
    #pragma unroll
    for (int o = 0; o < NH; ++o) {
        float s = sb2[o];
        #pragma unroll
        for (int i = 0; i < NH; ++i) s = fmaf(sW2[o * NH + i], l1[i], s);
        l2[o] = elu_f(s);
    }
    #pragma unroll
    for (int o = 0; o < NH; ++o) {
        float s = sb3[o];
        #pragma unroll
        for (int i = 0; i < NH; ++i) s = fmaf(sW3[o * NH + i], l2[i], s);
        hp[o] = elu_f(s);
    }

    float sqp = 0.f;
    #pragma unroll
    for (int i = 0; i < NH; ++i) sqp = fmaf(hp[i], hp[i], sqp);

    #pragma unroll
    for (int i = 0; i < NH; ++i) sh[t][i] = hp[i];
    sh[t][NH] = sqp;
    __syncthreads();

    // ---- kNN: top-8 smallest distances, tie -> smaller index ----
    // packed key: high 24 bits of float dist | 8-bit index. min/max sorted insert.
    // 2-way unrolled over j: two independent dot chains hide the insert chain.
    float bk[NK];
    #pragma unroll
    for (int s = 0; s < NK; ++s) bk[s] = __uint_as_float(0x7F7FFFFFu);

    for (int j = 0; j < NP; j += 2) {
        const float4* rowA = reinterpret_cast<const float4*>(&sh[j][0]);
        const float4* rowB = reinterpret_cast<const float4*>(&sh[j + 1][0]);
        float4 a0 = rowA[0], a1 = rowA[1], a2 = rowA[2], a3 = rowA[3];
        float4 c0 = rowB[0], c1 = rowB[1], c2 = rowB[2], c3 = rowB[3];
        float sqA = sh[j][NH];
        float sqB = sh[j + 1][NH];

        float dA = 0.f, dB = 0.f;
        dA = fmaf(hp[0],  a0.x, dA);  dB = fmaf(hp[0],  c0.x, dB);
        dA = fmaf(hp[1],  a0.y, dA);  dB = fmaf(hp[1],  c0.y, dB);
        dA = fmaf(hp[2],  a0.z, dA);  dB = fmaf(hp[2],  c0.z, dB);
        dA = fmaf(hp[3],  a0.w, dA);  dB = fmaf(hp[3],  c0.w, dB);
        dA = fmaf(hp[4],  a1.x, dA);  dB = fmaf(hp[4],  c1.x, dB);
        dA = fmaf(hp[5],  a1.y, dA);  dB = fmaf(hp[5],  c1.y, dB);
        dA = fmaf(hp[6],  a1.z, dA);  dB = fmaf(hp[6],  c1.z, dB);
        dA = fmaf(hp[7],  a1.w, dA);  dB = fmaf(hp[7],  c1.w, dB);
        dA = fmaf(hp[8],  a2.x, dA);  dB = fmaf(hp[8],  c2.x, dB);
        dA = fmaf(hp[9],  a2.y, dA);  dB = fmaf(hp[9],  c2.y, dB);
        dA = fmaf(hp[10], a2.z, dA);  dB = fmaf(hp[10], c2.z, dB);
        dA = fmaf(hp[11], a2.w, dA);  dB = fmaf(hp[11], c2.w, dB);
        dA = fmaf(hp[12], a3.x, dA);  dB = fmaf(hp[12], c3.x, dB);
        dA = fmaf(hp[13], a3.y, dA);  dB = fmaf(hp[13], c3.y, dB);
        dA = fmaf(hp[14], a3.z, dA);  dB = fmaf(hp[14], c3.z, dB);
        dA = fmaf(hp[15], a3.w, dA);  dB = fmaf(hp[15], c3.w, dB);

        float distA = fmaxf(fmaf(-2.f, dA, sqp + sqA), 0.f);
        float distB = fmaxf(fmaf(-2.f, dB, sqp + sqB), 0.f);
        float kfA = __uint_as_float((__float_as_uint(distA) & 0xFFFFFF00u) | (unsigned)j);
        float kfB = __uint_as_float((__float_as_uint(distB) & 0xFFFFFF00u) | (unsigned)(j + 1));

        #pragma unroll
        for (int s = 0; s < NK; ++s) {
            float lo = fminf(bk[s], kfA);
            kfA = fmaxf(bk[s], kfA);
            bk[s] = lo;
        }
        #pragma unroll
        for (int s = 0; s < NK; ++s) {
            float lo = fminf(bk[s], kfB);
            kfB = fmaxf(bk[s], kfB);
            bk[s] = lo;
        }
    }

    // pack the 8 neighbor indices into two u32 (frees bk before edge loop)
    unsigned idxlo = 0, idxhi = 0;
    #pragma unroll
    for (int s = 0; s < 4; ++s) idxlo |= (__float_as_uint(bk[s]) & 0xFFu) << (8 * s);
    #pragma unroll
    for (int s = 0; s < 4; ++s) idxhi |= (__float_as_uint(bk[s + 4]) & 0xFFu) << (8 * s);

    // ---- edge MLP + max aggregation ----
    // m[o] = ELU( be[o] + (We_a - We_b)[o]·xi + We_b[o]·xj )
    float base_[NH];
    #pragma unroll
    for (int o = 0; o < NH; ++o) {
        float s = sbe[o];
        #pragma unroll
        for (int i = 0; i < NH; ++i) s = fmaf(sWc[o * NH + i], hp[i], s);
        base_[o] = s;
    }

    float nodemax[NH];
    #pragma unroll
    for (int o = 0; o < NH; ++o) nodemax[o] = -INFINITY;

    #pragma unroll
    for (int k = 0; k < NK; ++k) {
        int j = (int)(((k < 4 ? idxlo : idxhi) >> (8 * (k & 3))) & 0xFFu);
        const float4* row = reinterpret_cast<const float4*>(&sh[j][0]);
        float4 r0 = row[0], r1 = row[1], r2 = row[2], r3 = row[3];
        #pragma unroll
        for (int o = 0; o < NH; ++o) {
            float s = base_[o];
            s = fmaf(sWb[o * NH + 0],  r0.x, s);
            s = fmaf(sWb[o * NH + 1],  r0.y, s);
            s = fmaf(sWb[o * NH + 2],  r0.z, s);
            s = fmaf(sWb[o * NH + 3],  r0.w, s);
            s = fmaf(sWb[o * NH + 4],  r1.x, s);
            s = fmaf(sWb[o * NH + 5],  r1.y, s);
            s = fmaf(sWb[o * NH + 6],  r1.z, s);
            s = fmaf(sWb[o * NH + 7],  r1.w, s);
            s = fmaf(sWb[o * NH + 8],  r2.x, s);
            s = fmaf(sWb[o * NH + 9],  r2.y, s);
            s = fmaf(sWb[o * NH + 10], r2.z, s);
            s = fmaf(sWb[o * NH + 11], r2.w, s);
            s = fmaf(sWb[o * NH + 12], r3.x, s);
            s = fmaf(sWb[o * NH + 13], r3.y, s);
            s = fmaf(sWb[o * NH + 14], r3.z, s);
            s = fmaf(sWb[o * NH + 15], r3.w, s);
            s = elu_f(s);
            nodemax[o] = fmaxf(nodemax[o], s);
        }
    }

    // ---- mean-pool over particles (LDS tree reduce, reuse sh) ----
    __syncthreads();   // everyone done gathering from sh
    #pragma unroll
    for (int i = 0; i < NH; ++i) sh[t][i] = nodemax[i];
    __syncthreads();
    for (int s = 128; s > 0; s >>= 1) {
        if (t < s) {
            #pragma unroll
            for (int i = 0; i < NH; ++i) sh[t][i] += sh[t + s][i];
        }
        __syncthreads();
    }

    // ---- head MLP + sigmoid (thread 0) ----
    if (t == 0) {
        float o1[8];
        #pragma unroll
        for (int o = 0; o < 8; ++o) {
            float s = sbo1[o];
            #pragma unroll
            for (int i = 0; i < NH; ++i) s = fmaf(sWo1[o * NH + i], sh[0][i] * (1.f / NP), s);
            o1[o] = elu_f(s);
        }
        float o2 = sbo2[0];
        #pragma unroll
        for (int i = 0; i < 8; ++i) o2 = fmaf(sWo2[i], o1[i], o2);
        gout[b] = 1.f / (1.f + expf(-o2));
    }
}

extern "C" void kernel_launch(void* const* d_in, const int* in_sizes, int n_in,
                              void* d_out, int out_size, void* d_ws, size_t ws_size,
                              hipStream_t stream) {
    const float* x   = (const float*)d_in[0];
    const float* W1  = (const float*)d_in[1];
    const float* W2  = (const float*)d_in[2];
    const float* b2  = (const float*)d_in[3];
    const float* W3  = (const float*)d_in[4];
    const float* b3  = (const float*)d_in[5];
    const float* We  = (const float*)d_in[6];
    const float* be  = (const float*)d_in[7];
    const float* Wo1 = (const float*)d_in[8];
    const float* bo1 = (const float*)d_in[9];
    const float* Wo2 = (const float*)d_in[10];
    const float* bo2 = (const float*)d_in[11];
    float* out = (float*)d_out;

    hipLaunchKernelGGL(edgenet_kernel, dim3(NB), dim3(NP), 0, stream,
                       x, W1, W2, b2, W3, b3, We, be, Wo1, bo1, Wo2, bo2, out);
}

// Round 3
// 333.345 us; speedup vs baseline: 1.6091x; 1.5722x over previous
//
#include <hip/hip_runtime.h>
#include <math.h>

#define NB 1024
#define NP 256
#define FIN 8
#define NH 16
#define NK 8

__device__ __forceinline__ float elu_f(float v) {
    return v > 0.f ? v : (__expf(v) - 1.f);
}

// No __launch_bounds__: it emits its own flat-work-group/waves metadata that
// appears to override amdgpu_waves_per_eu (R1/R2 evidence: VGPR stuck at 64,
// 403 MB scratch writes). min=2 waves/EU -> VGPR cap 256; max=4 -> allocator
// must not squeeze registers to chase 8 waves/EU.
__global__ __attribute__((amdgpu_flat_work_group_size(256, 256),
                          amdgpu_waves_per_eu(2, 4)))
void edgenet_kernel(
    const float* __restrict__ gx,
    const float* __restrict__ gW1, const float* __restrict__ gW2, const float* __restrict__ gb2,
    const float* __restrict__ gW3, const float* __restrict__ gb3,
    const float* __restrict__ gWe, const float* __restrict__ gbe,
    const float* __restrict__ gWo1, const float* __restrict__ gbo1,
    const float* __restrict__ gWo2, const float* __restrict__ gbo2,
    float* __restrict__ gout)
{
    const int b = blockIdx.x;
    const int t = threadIdx.x;

    __shared__ __align__(16) float sW1[NH * FIN];
    __shared__ __align__(16) float sW2[NH * NH];
    __shared__ __align__(16) float sW3[NH * NH];
    __shared__ __align__(16) float sWb[NH * NH];   // We[:,16:32]
    __shared__ __align__(16) float sWc[NH * NH];   // We[:,0:16] - We[:,16:32]
    __shared__ __align__(16) float sb2[NH], sb3[NH], sbe[NH];
    __shared__ __align__(16) float sWo1[8 * NH];
    __shared__ __align__(16) float sbo1[8], sWo2[8], sbo2[1];
    // h rows: [16 features][1 sq][3 pad] -> 20 floats = 80 B (16B aligned)
    __shared__ __align__(16) float sh[NP][20];

    // ---- cooperative weight staging ----
    if (t < NH * FIN) sW1[t] = gW1[t];
    sW2[t] = gW2[t];
    sW3[t] = gW3[t];
    {
        int o = t >> 4, i = t & 15;
        float a = gWe[o * 32 + i];
        float c = gWe[o * 32 + 16 + i];
        sWb[t] = c;
        sWc[t] = a - c;
    }
    if (t < NH) { sb2[t] = gb2[t]; sb3[t] = gb3[t]; sbe[t] = gbe[t]; }
    if (t < 8 * NH) sWo1[t] = gWo1[t];
    if (t < 8) { sbo1[t] = gbo1[t]; sWo2[t] = gWo2[t]; }
    if (t == 0) sbo2[0] = gbo2[0];

    // ---- load this thread's particle (8 floats, 2x float4, coalesced) ----
    float xin[FIN];
    {
        const float4* xr = reinterpret_cast<const float4*>(gx + (size_t)b * (NP * FIN) + t * FIN);
        float4 v0 = xr[0], v1 = xr[1];
        xin[0] = v0.x; xin[1] = v0.y; xin[2] = v0.z; xin[3] = v0.w;
        xin[4] = v1.x; xin[5] = v1.y; xin[6] = v1.z; xin[7] = v1.w;
    }
    __syncthreads();

    // ---- encoder MLP: 8 -> 16 -> 16 -> 16, ELU ----
    float l1[NH], l2[NH], hp[NH];
    #pragma unroll
    for (int o = 0; o < NH; ++o) {
        float s = 0.f;
        #pragma unroll
        for (int i = 0; i < FIN; ++i) s = fmaf(sW1[o * FIN + i], xin[i], s);
        l1[o] = elu_f(s);
    }
    #pragma unroll
    for (int o = 0; o < NH; ++o) {
        float s = sb2[o];
        #pragma unroll
        for (int i = 0; i < NH; ++i) s = fmaf(sW2[o * NH + i], l1[i], s);
        l2[o] = elu_f(s);
    }
    #pragma unroll
    for (int o = 0; o < NH; ++o) {
        float s = sb3[o];
        #pragma unroll
        for (int i = 0; i < NH; ++i) s = fmaf(sW3[o * NH + i], l2[i], s);
        hp[o] = elu_f(s);
    }

    float sqp = 0.f;
    #pragma unroll
    for (int i = 0; i < NH; ++i) sqp = fmaf(hp[i], hp[i], sqp);

    #pragma unroll
    for (int i = 0; i < NH; ++i) sh[t][i] = hp[i];
    sh[t][NH] = sqp;
    __syncthreads();

    // ---- kNN: top-8 smallest distances, tie -> smaller index ----
    // packed key: high 24 bits of float dist | 8-bit index. min/max sorted insert.
    float bk[NK];
    #pragma unroll
    for (int s = 0; s < NK; ++s) bk[s] = __uint_as_float(0x7F7FFFFFu);

    for (int j = 0; j < NP; ++j) {
        const float4* row = reinterpret_cast<const float4*>(&sh[j][0]);
        float4 r0 = row[0], r1 = row[1], r2 = row[2], r3 = row[3];
        float sqj = sh[j][NH];
        float dot = 0.f;
        dot = fmaf(hp[0],  r0.x, dot); dot = fmaf(hp[1],  r0.y, dot);
        dot = fmaf(hp[2],  r0.z, dot); dot = fmaf(hp[3],  r0.w, dot);
        dot = fmaf(hp[4],  r1.x, dot); dot = fmaf(hp[5],  r1.y, dot);
        dot = fmaf(hp[6],  r1.z, dot); dot = fmaf(hp[7],  r1.w, dot);
        dot = fmaf(hp[8],  r2.x, dot); dot = fmaf(hp[9],  r2.y, dot);
        dot = fmaf(hp[10], r2.z, dot); dot = fmaf(hp[11], r2.w, dot);
        dot = fmaf(hp[12], r3.x, dot); dot = fmaf(hp[13], r3.y, dot);
        dot = fmaf(hp[14], r3.z, dot); dot = fmaf(hp[15], r3.w, dot);
        float d = fmaf(-2.f, dot, sqp + sqj);
        d = fmaxf(d, 0.f);
        float kf = __uint_as_float((__float_as_uint(d) & 0xFFFFFF00u) | (unsigned)j);
        #pragma unroll
        for (int s = 0; s < NK; ++s) {
            float lo = fminf(bk[s], kf);
            kf = fmaxf(bk[s], kf);
            bk[s] = lo;
        }
    }

    // pack the 8 neighbor indices into two u32 (frees bk before edge loop)
    unsigned idxlo = 0, idxhi = 0;
    #pragma unroll
    for (int s = 0; s < 4; ++s) idxlo |= (__float_as_uint(bk[s]) & 0xFFu) << (8 * s);
    #pragma unroll
    for (int s = 0; s < 4; ++s) idxhi |= (__float_as_uint(bk[s + 4]) & 0xFFu) << (8 * s);

    // ---- edge MLP + max aggregation ----
    // m[o] = ELU( be[o] + (We_a - We_b)[o]·xi + We_b[o]·xj )
    float base_[NH];
    #pragma unroll
    for (int o = 0; o < NH; ++o) {
        float s = sbe[o];
        #pragma unroll
        for (int i = 0; i < NH; ++i) s = fmaf(sWc[o * NH + i], hp[i], s);
        base_[o] = s;
    }

    float nodemax[NH];
    #pragma unroll
    for (int o = 0; o < NH; ++o) nodemax[o] = -INFINITY;

    #pragma unroll
    for (int k = 0; k < NK; ++k) {
        int j = (int)(((k < 4 ? idxlo : idxhi) >> (8 * (k & 3))) & 0xFFu);
        const float4* row = reinterpret_cast<const float4*>(&sh[j][0]);
        float4 r0 = row[0], r1 = row[1], r2 = row[2], r3 = row[3];
        #pragma unroll
        for (int o = 0; o < NH; ++o) {
            float s = base_[o];
            s = fmaf(sWb[o * NH + 0],  r0.x, s);
            s = fmaf(sWb[o * NH + 1],  r0.y, s);
            s = fmaf(sWb[o * NH + 2],  r0.z, s);
            s = fmaf(sWb[o * NH + 3],  r0.w, s);
            s = fmaf(sWb[o * NH + 4],  r1.x, s);
            s = fmaf(sWb[o * NH + 5],  r1.y, s);
            s = fmaf(sWb[o * NH + 6],  r1.z, s);
            s = fmaf(sWb[o * NH + 7],  r1.w, s);
            s = fmaf(sWb[o * NH + 8],  r2.x, s);
            s = fmaf(sWb[o * NH + 9],  r2.y, s);
            s = fmaf(sWb[o * NH + 10], r2.z, s);
            s = fmaf(sWb[o * NH + 11], r2.w, s);
            s = fmaf(sWb[o * NH + 12], r3.x, s);
            s = fmaf(sWb[o * NH + 13], r3.y, s);
            s = fmaf(sWb[o * NH + 14], r3.z, s);
            s = fmaf(sWb[o * NH + 15], r3.w, s);
            s = elu_f(s);
            nodemax[o] = fmaxf(nodemax[o], s);
        }
    }

    // ---- mean-pool over particles (LDS tree reduce, reuse sh) ----
    __syncthreads();   // everyone done gathering from sh
    #pragma unroll
    for (int i = 0; i < NH; ++i) sh[t][i] = nodemax[i];
    __syncthreads();
    for (int s = 128; s > 0; s >>= 1) {
        if (t < s) {
            #pragma unroll
            for (int i = 0; i < NH; ++i) sh[t][i] += sh[t + s][i];
        }
        __syncthreads();
    }

    // ---- head MLP + sigmoid (thread 0) ----
    if (t == 0) {
        float o1[8];
        #pragma unroll
        for (int o = 0; o < 8; ++o) {
            float s = sbo1[o];
            #pragma unroll
            for (int i = 0; i < NH; ++i) s = fmaf(sWo1[o * NH + i], sh[0][i] * (1.f / NP), s);
            o1[o] = elu_f(s);
        }
        float o2 = sbo2[0];
        #pragma unroll
        for (int i = 0; i < 8; ++i) o2 = fmaf(sWo2[i], o1[i], o2);
        gout[b] = 1.f / (1.f + expf(-o2));
    }
}

extern "C" void kernel_launch(void* const* d_in, const int* in_sizes, int n_in,
                              void* d_out, int out_size, void* d_ws, size_t ws_size,
                              hipStream_t stream) {
    const float* x   = (const float*)d_in[0];
    const float* W1  = (const float*)d_in[1];
    const float* W2  = (const float*)d_in[2];
    const float* b2  = (const float*)d_in[3];
    const float* W3  = (const float*)d_in[4];
    const float* b3  = (const float*)d_in[5];
    const float* We  = (const float*)d_in[6];
    const float* be  = (const float*)d_in[7];
    const float* Wo1 = (const float*)d_in[8];
    const float* bo1 = (const float*)d_in[9];
    const float* Wo2 = (const float*)d_in[10];
    const float* bo2 = (const float*)d_in[11];
    float* out = (float*)d_out;

    hipLaunchKernelGGL(edgenet_kernel, dim3(NB), dim3(NP), 0, stream,
                       x, W1, W2, b2, W3, b3, We, be, Wo1, bo1, Wo2, bo2, out);
}

// Round 4
// 236.595 us; speedup vs baseline: 2.2671x; 1.4089x over previous
//
#include <hip/hip_runtime.h>
#include <math.h>

#define NB 1024
#define NP 256
#define FIN 8
#define NH 16
#define NK 8

#define REP8A(X)  X(0) X(1) X(2) X(3) X(4) X(5) X(6) X(7)
#define REP16A(X) X(0) X(1) X(2) X(3) X(4) X(5) X(6) X(7) X(8) X(9) X(10) X(11) X(12) X(13) X(14) X(15)
#define REP16B(X) X(0) X(1) X(2) X(3) X(4) X(5) X(6) X(7) X(8) X(9) X(10) X(11) X(12) X(13) X(14) X(15)

__device__ __forceinline__ float elu_f(float v) {
    return v > 0.f ? v : (__expf(v) - 1.f);
}

// All per-thread state is individually-named scalars: no private arrays exist,
// so no array-to-scratch lowering is possible (R3 evidence: 381 MB HBM writes
// at VGPR=128 despite ~55-reg live set).
__global__ __attribute__((amdgpu_flat_work_group_size(256, 256),
                          amdgpu_waves_per_eu(2, 4)))
void edgenet_kernel(
    const float* __restrict__ gx,
    const float* __restrict__ gW1, const float* __restrict__ gW2, const float* __restrict__ gb2,
    const float* __restrict__ gW3, const float* __restrict__ gb3,
    const float* __restrict__ gWe, const float* __restrict__ gbe,
    const float* __restrict__ gWo1, const float* __restrict__ gbo1,
    const float* __restrict__ gWo2, const float* __restrict__ gbo2,
    float* __restrict__ gout)
{
    const int b = blockIdx.x;
    const int t = threadIdx.x;

    __shared__ __align__(16) float sW1[NH * FIN];
    __shared__ __align__(16) float sW2[NH * NH];
    __shared__ __align__(16) float sW3[NH * NH];
    __shared__ __align__(16) float sWb[NH * NH];   // We[:,16:32]
    __shared__ __align__(16) float sWc[NH * NH];   // We[:,0:16] - We[:,16:32]
    __shared__ __align__(16) float sb2[NH], sb3[NH], sbe[NH];
    __shared__ __align__(16) float sWo1[8 * NH];
    __shared__ __align__(16) float sbo1[8], sWo2[8], sbo2[1];
    // h rows: [16 features][1 sq][3 pad] -> 80 B rows, 16B aligned
    __shared__ __align__(16) float sh[NP][20];

    // ---- cooperative weight staging ----
    if (t < NH * FIN) sW1[t] = gW1[t];
    sW2[t] = gW2[t];
    sW3[t] = gW3[t];
    {
        int o = t >> 4, i = t & 15;
        float a = gWe[o * 32 + i];
        float c = gWe[o * 32 + 16 + i];
        sWb[t] = c;
        sWc[t] = a - c;
    }
    if (t < NH) { sb2[t] = gb2[t]; sb3[t] = gb3[t]; sbe[t] = gbe[t]; }
    if (t < 8 * NH) sWo1[t] = gWo1[t];
    if (t < 8) { sbo1[t] = gbo1[t]; sWo2[t] = gWo2[t]; }
    if (t == 0) sbo2[0] = gbo2[0];

    // ---- load particle (named scalars) ----
    float xi0, xi1, xi2, xi3, xi4, xi5, xi6, xi7;
    {
        const float4* xr = reinterpret_cast<const float4*>(gx + (size_t)b * (NP * FIN) + t * FIN);
        float4 v0 = xr[0], v1 = xr[1];
        xi0 = v0.x; xi1 = v0.y; xi2 = v0.z; xi3 = v0.w;
        xi4 = v1.x; xi5 = v1.y; xi6 = v1.z; xi7 = v1.w;
    }
    __syncthreads();

    // ---- encoder MLP: 8 -> 16 -> 16 -> 16, ELU, all named scalars ----
    float l1_0,l1_1,l1_2,l1_3,l1_4,l1_5,l1_6,l1_7,l1_8,l1_9,l1_10,l1_11,l1_12,l1_13,l1_14,l1_15;
    float l2_0,l2_1,l2_2,l2_3,l2_4,l2_5,l2_6,l2_7,l2_8,l2_9,l2_10,l2_11,l2_12,l2_13,l2_14,l2_15;
    float hp0,hp1,hp2,hp3,hp4,hp5,hp6,hp7,hp8,hp9,hp10,hp11,hp12,hp13,hp14,hp15;

#define L1_BODY(i) s = fmaf(w1r[i], xi##i, s);
#define L1_O(o) { const float* w1r = &sW1[(o) * FIN]; float s = 0.f; REP8A(L1_BODY) l1_##o = elu_f(s); }
    REP16A(L1_O)
#undef L1_O

#define L2_BODY(i) s = fmaf(w2r[i], l1_##i, s);
#define L2_O(o) { const float* w2r = &sW2[(o) * NH]; float s = sb2[o]; REP16B(L2_BODY) l2_##o = elu_f(s); }
    REP16A(L2_O)
#undef L2_O

#define L3_BODY(i) s = fmaf(w3r[i], l2_##i, s);
#define L3_O(o) { const float* w3r = &sW3[(o) * NH]; float s = sb3[o]; REP16B(L3_BODY) hp##o = elu_f(s); }
    REP16A(L3_O)
#undef L3_O

    float sqp = 0.f;
#define SQ_I(i) sqp = fmaf(hp##i, hp##i, sqp);
    REP16A(SQ_I)
#undef SQ_I

#define ST_I(i) sh[t][i] = hp##i;
    REP16A(ST_I)
#undef ST_I
    sh[t][NH] = sqp;
    __syncthreads();

    // ---- kNN: top-8 smallest distances, tie -> smaller index ----
    // packed key: high 24 bits of dist | 8-bit index; 8 named slots, min/max insert.
    float bk0, bk1, bk2, bk3, bk4, bk5, bk6, bk7;
    bk0 = bk1 = bk2 = bk3 = bk4 = bk5 = bk6 = bk7 = __uint_as_float(0x7F7FFFFFu);

    for (int j = 0; j < NP; ++j) {
        const float4* row = reinterpret_cast<const float4*>(&sh[j][0]);
        float4 r0 = row[0], r1 = row[1], r2 = row[2], r3 = row[3];
        float sqj = sh[j][NH];
        float dot = 0.f;
        dot = fmaf(hp0,  r0.x, dot); dot = fmaf(hp1,  r0.y, dot);
        dot = fmaf(hp2,  r0.z, dot); dot = fmaf(hp3,  r0.w, dot);
        dot = fmaf(hp4,  r1.x, dot); dot = fmaf(hp5,  r1.y, dot);
        dot = fmaf(hp6,  r1.z, dot); dot = fmaf(hp7,  r1.w, dot);
        dot = fmaf(hp8,  r2.x, dot); dot = fmaf(hp9,  r2.y, dot);
        dot = fmaf(hp10, r2.z, dot); dot = fmaf(hp11, r2.w, dot);
        dot = fmaf(hp12, r3.x, dot); dot = fmaf(hp13, r3.y, dot);
        dot = fmaf(hp14, r3.z, dot); dot = fmaf(hp15, r3.w, dot);
        float d = fmaxf(fmaf(-2.f, dot, sqp + sqj), 0.f);
        float kf = __uint_as_float((__float_as_uint(d) & 0xFFFFFF00u) | (unsigned)j);
#define INS(s_) { float lo_ = fminf(bk##s_, kf); kf = fmaxf(bk##s_, kf); bk##s_ = lo_; }
        REP8A(INS)
#undef INS
    }

    // 8 named neighbor indices; bk dies here
#define JX(i) const int j##i = (int)(__float_as_uint(bk##i) & 0xFFu);
    REP8A(JX)
#undef JX

    // ---- edge MLP + max aggregation ----
    // m[o] = ELU( be[o] + (We_a - We_b)[o]·xi + We_b[o]·xj )
    float base0,base1,base2,base3,base4,base5,base6,base7,
          base8,base9,base10,base11,base12,base13,base14,base15;
#define BAS_BODY(i) s = fmaf(wcr[i], hp##i, s);
#define BAS_O(o) { const float* wcr = &sWc[(o) * NH]; float s = sbe[o]; REP16B(BAS_BODY) base##o = s; }
    REP16A(BAS_O)
#undef BAS_O

    float nm0,nm1,nm2,nm3,nm4,nm5,nm6,nm7,nm8,nm9,nm10,nm11,nm12,nm13,nm14,nm15;
    nm0=nm1=nm2=nm3=nm4=nm5=nm6=nm7=nm8=nm9=nm10=nm11=nm12=nm13=nm14=nm15 = -INFINITY;

#define EDG_BODY(i) s = fmaf(wbr[i], rv##i, s);
#define EDG_O(o) { const float* wbr = &sWb[(o) * NH]; float s = base##o; REP16B(EDG_BODY) \
                   s = elu_f(s); nm##o = fmaxf(nm##o, s); }
#define EDGE_K(k) { const float4* row = reinterpret_cast<const float4*>(&sh[j##k][0]); \
    float4 e0 = row[0], e1 = row[1], e2 = row[2], e3 = row[3]; \
    const float rv0 = e0.x, rv1 = e0.y, rv2 = e0.z, rv3 = e0.w; \
    const float rv4 = e1.x, rv5 = e1.y, rv6 = e1.z, rv7 = e1.w; \
    const float rv8 = e2.x, rv9 = e2.y, rv10 = e2.z, rv11 = e2.w; \
    const float rv12 = e3.x, rv13 = e3.y, rv14 = e3.z, rv15 = e3.w; \
    REP16A(EDG_O) }
    REP8A(EDGE_K)
#undef EDGE_K
#undef EDG_O
#undef EDG_BODY

    // ---- mean-pool over particles (LDS tree reduce, reuse sh) ----
    __syncthreads();   // everyone done gathering from sh
#define NMS(i) sh[t][i] = nm##i;
    REP16A(NMS)
#undef NMS
    __syncthreads();
    for (int s = 128; s > 0; s >>= 1) {
        if (t < s) {
            #pragma unroll
            for (int i = 0; i < NH; ++i) sh[t][i] += sh[t + s][i];
        }
        __syncthreads();
    }

    // ---- head MLP + sigmoid (thread 0) ----
    if (t == 0) {
        float o1_0,o1_1,o1_2,o1_3,o1_4,o1_5,o1_6,o1_7;
#define HD_BODY(i) s = fmaf(wor[i], sh[0][i] * (1.f / NP), s);
#define HD_O(o) { const float* wor = &sWo1[(o) * NH]; float s = sbo1[o]; REP16B(HD_BODY) o1_##o = elu_f(s); }
        REP8A(HD_O)
#undef HD_O
#undef HD_BODY
        float o2 = sbo2[0];
        o2 = fmaf(sWo2[0], o1_0, o2); o2 = fmaf(sWo2[1], o1_1, o2);
        o2 = fmaf(sWo2[2], o1_2, o2); o2 = fmaf(sWo2[3], o1_3, o2);
        o2 = fmaf(sWo2[4], o1_4, o2); o2 = fmaf(sWo2[5], o1_5, o2);
        o2 = fmaf(sWo2[6], o1_6, o2); o2 = fmaf(sWo2[7], o1_7, o2);
        gout[b] = 1.f / (1.f + expf(-o2));
    }
}

extern "C" void kernel_launch(void* const* d_in, const int* in_sizes, int n_in,
                              void* d_out, int out_size, void* d_ws, size_t ws_size,
                              hipStream_t stream) {
    const float* x   = (const float*)d_in[0];
    const float* W1  = (const float*)d_in[1];
    const float* W2  = (const float*)d_in[2];
    const float* b2  = (const float*)d_in[3];
    const float* W3  = (const float*)d_in[4];
    const float* b3  = (const float*)d_in[5];
    const float* We  = (const float*)d_in[6];
    const float* be  = (const float*)d_in[7];
    const float* Wo1 = (const float*)d_in[8];
    const float* bo1 = (const float*)d_in[9];
    const float* Wo2 = (const float*)d_in[10];
    const float* bo2 = (const float*)d_in[11];
    float* out = (float*)d_out;

    hipLaunchKernelGGL(edgenet_kernel, dim3(NB), dim3(NP), 0, stream,
                       x, W1, W2, b2, W3, b3, We, be, Wo1, bo1, Wo2, bo2, out);
}

// Round 5
// 193.065 us; speedup vs baseline: 2.7783x; 1.2255x over previous
//
#include <hip/hip_runtime.h>
#include <math.h>

#define NB 1024
#define NP 256
#define FIN 8
#define NH 16
#define NK 8

#define REP8A(X)  X(0) X(1) X(2) X(3) X(4) X(5) X(6) X(7)
#define REP16A(X) X(0) X(1) X(2) X(3) X(4) X(5) X(6) X(7) X(8) X(9) X(10) X(11) X(12) X(13) X(14) X(15)
#define REP16B(X) X(0) X(1) X(2) X(3) X(4) X(5) X(6) X(7) X(8) X(9) X(10) X(11) X(12) X(13) X(14) X(15)

typedef short s8v __attribute__((ext_vector_type(8)));
typedef float f4v __attribute__((ext_vector_type(4)));
typedef unsigned int u4v __attribute__((ext_vector_type(4)));

__device__ __forceinline__ float elu_f(float v) {
    return v > 0.f ? v : (__expf(v) - 1.f);
}
__device__ __forceinline__ unsigned bf16r(float f) {   // round-to-nearest-even bf16 bits
    unsigned u = __float_as_uint(f);
    return (u + 0x7FFFu + ((u >> 16) & 1u)) >> 16;
}
__device__ __forceinline__ float ush2f(unsigned short u) {
    return __uint_as_float(((unsigned)u) << 16);
}

__global__ __attribute__((amdgpu_flat_work_group_size(256, 256),
                          amdgpu_waves_per_eu(2, 4)))
void edgenet_kernel(
    const float* __restrict__ gx,
    const float* __restrict__ gW1, const float* __restrict__ gW2, const float* __restrict__ gb2,
    const float* __restrict__ gW3, const float* __restrict__ gb3,
    const float* __restrict__ gWe, const float* __restrict__ gbe,
    const float* __restrict__ gWo1, const float* __restrict__ gbo1,
    const float* __restrict__ gWo2, const float* __restrict__ gbo2,
    float* __restrict__ gout)
{
    const int b  = blockIdx.x;
    const int t  = threadIdx.x;
    const int w  = t >> 6;          // wave id (0..3)
    const int lq = (t >> 4) & 3;    // k-chunk group of lane
    const int lc = t & 15;          // row/col-in-tile of lane

    // ---- LDS ----
    __shared__ float sWb[256], sWc[256], sbe[16];
    __shared__ float sWo1[128], sbo1[8], sWo2[8], sbo2v[1];
    // split-bf16 fragment store: [particle-tile][q][lane-chunk 8 ush + pad]
    // chunk (tile,q,c) holds [a(4q..4q+3) | b(4q..4q+3)] of particle 16*tile+c
    __shared__ __align__(16) unsigned short hF[16][4][136];
    __shared__ float sqarr[256];
    // multi-use: encoder weights -> per-wave S panels [4][64][18] -> pool scratch
    __shared__ __align__(16) float sbuf[4608];
    float* enc = sbuf;

    // ---- weight staging ----
    {
        int o = t >> 4, i = t & 15;
        float aa = gWe[o * 32 + i];
        float cc = gWe[o * 32 + 16 + i];
        sWb[t] = cc;            // We[:,16:32]
        sWc[t] = aa - cc;       // We[:,0:16] - We[:,16:32]
    }
    if (t < 128) { enc[t] = gW1[t]; sWo1[t] = gWo1[t]; }
    enc[128 + t] = gW2[t];
    enc[384 + t] = gW3[t];
    if (t < 16) { sbe[t] = gbe[t]; enc[640 + t] = gb2[t]; enc[656 + t] = gb3[t]; }
    if (t < 8)  { sbo1[t] = gbo1[t]; sWo2[t] = gWo2[t]; }
    if (t == 0) sbo2v[0] = gbo2[0];

    // ---- load particle ----
    float xi0, xi1, xi2, xi3, xi4, xi5, xi6, xi7;
    {
        const float4* xr = reinterpret_cast<const float4*>(gx + (size_t)b * (NP * FIN) + t * FIN);
        float4 v0 = xr[0], v1 = xr[1];
        xi0 = v0.x; xi1 = v0.y; xi2 = v0.z; xi3 = v0.w;
        xi4 = v1.x; xi5 = v1.y; xi6 = v1.z; xi7 = v1.w;
    }
    __syncthreads();

    // ---- encoder MLP 8->16->16->16 (weights from enc overlay) ----
    float l1_0,l1_1,l1_2,l1_3,l1_4,l1_5,l1_6,l1_7,l1_8,l1_9,l1_10,l1_11,l1_12,l1_13,l1_14,l1_15;
    float l2_0,l2_1,l2_2,l2_3,l2_4,l2_5,l2_6,l2_7,l2_8,l2_9,l2_10,l2_11,l2_12,l2_13,l2_14,l2_15;
    float hp0,hp1,hp2,hp3,hp4,hp5,hp6,hp7,hp8,hp9,hp10,hp11,hp12,hp13,hp14,hp15;

#define L1_BODY(i) s = fmaf(w1r[i], xi##i, s);
#define L1_O(o) { const float* w1r = &enc[(o) * FIN]; float s = 0.f; REP8A(L1_BODY) l1_##o = elu_f(s); }
    REP16A(L1_O)
#undef L1_O
#define L2_BODY(i) s = fmaf(w2r[i], l1_##i, s);
#define L2_O(o) { const float* w2r = &enc[128 + (o) * NH]; float s = enc[640 + (o)]; REP16B(L2_BODY) l2_##o = elu_f(s); }
    REP16A(L2_O)
#undef L2_O
#define L3_BODY(i) s = fmaf(w3r[i], l2_##i, s);
#define L3_O(o) { const float* w3r = &enc[384 + (o) * NH]; float s = enc[656 + (o)]; REP16B(L3_BODY) hp##o = elu_f(s); }
    REP16A(L3_O)
#undef L3_O

    float sqp = 0.f;
#define SQ_I(i) sqp = fmaf(hp##i, hp##i, sqp);
    REP16A(SQ_I)
#undef SQ_I

    // ---- bf16 hi/lo split, store fragment-native ----
#define PACKQ(q, A, B, C, D) { \
    unsigned ha = bf16r(hp##A), hb = bf16r(hp##B), hc = bf16r(hp##C), hd = bf16r(hp##D); \
    float ra = hp##A - ush2f((unsigned short)ha); \
    float rb = hp##B - ush2f((unsigned short)hb); \
    float rc = hp##C - ush2f((unsigned short)hc); \
    float rd = hp##D - ush2f((unsigned short)hd); \
    unsigned la = bf16r(ra), lb = bf16r(rb), lcc = bf16r(rc), ld = bf16r(rd); \
    u4v pk; pk.x = ha | (hb << 16); pk.y = hc | (hd << 16); \
            pk.z = la | (lb << 16); pk.w = lcc | (ld << 16); \
    *(u4v*)&hF[t >> 4][q][(t & 15) * 8] = pk; }
    PACKQ(0, 0, 1, 2, 3)
    PACKQ(1, 4, 5, 6, 7)
    PACKQ(2, 8, 9, 10, 11)
    PACKQ(3, 12, 13, 14, 15)
#undef PACKQ
    sqarr[t] = sqp;
    __syncthreads();

    // ---- hoisted A-fragments: wave w owns itiles 4w..4w+3 (rows 64w..64w+63) ----
    const s8v af0 = *(const s8v*)&hF[4 * w + 0][lq][lc * 8];
    const s8v af1 = *(const s8v*)&hF[4 * w + 1][lq][lc * 8];
    const s8v af2 = *(const s8v*)&hF[4 * w + 2][lq][lc * 8];
    const s8v af3 = *(const s8v*)&hF[4 * w + 3][lq][lc * 8];

    // ---- kNN: Gram panels via MFMA + packed-key dual-list select ----
    float bkE0, bkE1, bkE2, bkE3, bkE4, bkE5, bkE6, bkE7;
    float bkO0, bkO1, bkO2, bkO3, bkO4, bkO5, bkO6, bkO7;
    bkE0=bkE1=bkE2=bkE3=bkE4=bkE5=bkE6=bkE7 = __uint_as_float(0x7F7FFFFFu);
    bkO0=bkO1=bkO2=bkO3=bkO4=bkO5=bkO6=bkO7 = __uint_as_float(0x7F7FFFFFu);

    const int rr = t & 63;
    float* srow = &sbuf[w * 1152 + rr * 18];
    float* swr  = &sbuf[w * 1152 + lc];

    for (int jt = 0; jt < 16; ++jt) {
        const s8v bf1 = *(const s8v*)&hF[jt][lq][lc * 8];
        const s8v bf2 = __builtin_shufflevector(bf1, bf1, 4, 5, 6, 7, 0, 1, 2, 3);
        f4v z = {0.f, 0.f, 0.f, 0.f};
        f4v ac0 = __builtin_amdgcn_mfma_f32_16x16x32_bf16(af0, bf1, z, 0, 0, 0);
        ac0     = __builtin_amdgcn_mfma_f32_16x16x32_bf16(af0, bf2, ac0, 0, 0, 0);
        f4v ac1 = __builtin_amdgcn_mfma_f32_16x16x32_bf16(af1, bf1, z, 0, 0, 0);
        ac1     = __builtin_amdgcn_mfma_f32_16x16x32_bf16(af1, bf2, ac1, 0, 0, 0);
        f4v ac2 = __builtin_amdgcn_mfma_f32_16x16x32_bf16(af2, bf1, z, 0, 0, 0);
        ac2     = __builtin_amdgcn_mfma_f32_16x16x32_bf16(af2, bf2, ac2, 0, 0, 0);
        f4v ac3 = __builtin_amdgcn_mfma_f32_16x16x32_bf16(af3, bf1, z, 0, 0, 0);
        ac3     = __builtin_amdgcn_mfma_f32_16x16x32_bf16(af3, bf2, ac3, 0, 0, 0);

        // scatter S tiles to this wave's panel: D row = 4*lq + r, col = lc  (m89)
#define WS(tt, r) swr[(16 * (tt) + 4 * lq + (r)) * 18] = ac##tt[r];
        WS(0,0) WS(0,1) WS(0,2) WS(0,3)
        WS(1,0) WS(1,1) WS(1,2) WS(1,3)
        WS(2,0) WS(2,1) WS(2,2) WS(2,3)
        WS(3,0) WS(3,1) WS(3,2) WS(3,3)
#undef WS

        // select: thread t scans its own row (16 candidates of this panel)
        const float4 sqA = *(const float4*)&sqarr[16 * jt + 0];
        const float4 sqB = *(const float4*)&sqarr[16 * jt + 4];
        const float4 sqC = *(const float4*)&sqarr[16 * jt + 8];
        const float4 sqD = *(const float4*)&sqarr[16 * jt + 12];
        const float2 p0 = *(const float2*)&srow[0],  p1 = *(const float2*)&srow[2];
        const float2 p2 = *(const float2*)&srow[4],  p3 = *(const float2*)&srow[6];
        const float2 p4 = *(const float2*)&srow[8],  p5 = *(const float2*)&srow[10];
        const float2 p6 = *(const float2*)&srow[12], p7 = *(const float2*)&srow[14];
        const int jt16 = jt * 16;

#define INS1(L, s_, kf) { float lo_ = fminf(L##s_, kf); kf = fmaxf(L##s_, kf); L##s_ = lo_; }
#define INS8(L, kf) INS1(L,0,kf) INS1(L,1,kf) INS1(L,2,kf) INS1(L,3,kf) \
                    INS1(L,4,kf) INS1(L,5,kf) INS1(L,6,kf) INS1(L,7,kf)
#define CAND(c, sv, sqc, LIST) { \
    float d_ = fmaf(-2.f, (sv), sqp + (sqc)); \
    float kf_ = __uint_as_float((__float_as_uint(d_) & 0xFFFFFF00u) | (unsigned)(jt16 + (c))); \
    INS8(LIST, kf_) }
        CAND(0,  p0.x, sqA.x, bkE)  CAND(1,  p0.y, sqA.y, bkO)
        CAND(2,  p1.x, sqA.z, bkE)  CAND(3,  p1.y, sqA.w, bkO)
        CAND(4,  p2.x, sqB.x, bkE)  CAND(5,  p2.y, sqB.y, bkO)
        CAND(6,  p3.x, sqB.z, bkE)  CAND(7,  p3.y, sqB.w, bkO)
        CAND(8,  p4.x, sqC.x, bkE)  CAND(9,  p4.y, sqC.y, bkO)
        CAND(10, p5.x, sqC.z, bkE)  CAND(11, p5.y, sqC.w, bkO)
        CAND(12, p6.x, sqD.x, bkE)  CAND(13, p6.y, sqD.y, bkO)
        CAND(14, p7.x, sqD.z, bkE)  CAND(15, p7.y, sqD.w, bkO)
#undef CAND
#undef INS8
#undef INS1
    }

    // ---- merge E/O (bitonic lower half = top-8 set), extract indices ----
    const float m0 = fminf(bkE0, bkO7), m1 = fminf(bkE1, bkO6);
    const float m2 = fminf(bkE2, bkO5), m3 = fminf(bkE3, bkO4);
    const float m4 = fminf(bkE4, bkO3), m5 = fminf(bkE5, bkO2);
    const float m6 = fminf(bkE6, bkO1), m7 = fminf(bkE7, bkO0);
#define JX(i) const int j##i = (int)(__float_as_uint(m##i) & 0xFFu);
    REP8A(JX)
#undef JX

    // ---- edge MLP + max aggregation ----
    float base0,base1,base2,base3,base4,base5,base6,base7,
          base8,base9,base10,base11,base12,base13,base14,base15;
#define BAS_BODY(i) s = fmaf(wcr[i], hp##i, s);
#define BAS_O(o) { const float* wcr = &sWc[(o) * NH]; float s = sbe[o]; REP16B(BAS_BODY) base##o = s; }
    REP16A(BAS_O)
#undef BAS_O
#undef BAS_BODY

    float nm0,nm1,nm2,nm3,nm4,nm5,nm6,nm7,nm8,nm9,nm10,nm11,nm12,nm13,nm14,nm15;
    nm0=nm1=nm2=nm3=nm4=nm5=nm6=nm7=nm8=nm9=nm10=nm11=nm12=nm13=nm14=nm15 = -INFINITY;

#define EDG_BODY(i) s = fmaf(wbr[i], rv##i, s);
#define EDG_O(o) { const float* wbr = &sWb[(o) * NH]; float s = base##o; REP16B(EDG_BODY) \
                   s = elu_f(s); nm##o = fmaxf(nm##o, s); }
#define EDGE_K(X) { \
    const s8v c0_ = *(const s8v*)&hF[j##X >> 4][0][(j##X & 15) * 8]; \
    const s8v c1_ = *(const s8v*)&hF[j##X >> 4][1][(j##X & 15) * 8]; \
    const s8v c2_ = *(const s8v*)&hF[j##X >> 4][2][(j##X & 15) * 8]; \
    const s8v c3_ = *(const s8v*)&hF[j##X >> 4][3][(j##X & 15) * 8]; \
    const float rv0  = ush2f((unsigned short)c0_[0]) + ush2f((unsigned short)c0_[4]); \
    const float rv1  = ush2f((unsigned short)c0_[1]) + ush2f((unsigned short)c0_[5]); \
    const float rv2  = ush2f((unsigned short)c0_[2]) + ush2f((unsigned short)c0_[6]); \
    const float rv3  = ush2f((unsigned short)c0_[3]) + ush2f((unsigned short)c0_[7]); \
    const float rv4  = ush2f((unsigned short)c1_[0]) + ush2f((unsigned short)c1_[4]); \
    const float rv5  = ush2f((unsigned short)c1_[1]) + ush2f((unsigned short)c1_[5]); \
    const float rv6  = ush2f((unsigned short)c1_[2]) + ush2f((unsigned short)c1_[6]); \
    const float rv7  = ush2f((unsigned short)c1_[3]) + ush2f((unsigned short)c1_[7]); \
    const float rv8  = ush2f((unsigned short)c2_[0]) + ush2f((unsigned short)c2_[4]); \
    const float rv9  = ush2f((unsigned short)c2_[1]) + ush2f((unsigned short)c2_[5]); \
    const float rv10 = ush2f((unsigned short)c2_[2]) + ush2f((unsigned short)c2_[6]); \
    const float rv11 = ush2f((unsigned short)c2_[3]) + ush2f((unsigned short)c2_[7]); \
    const float rv12 = ush2f((unsigned short)c3_[0]) + ush2f((unsigned short)c3_[4]); \
    const float rv13 = ush2f((unsigned short)c3_[1]) + ush2f((unsigned short)c3_[5]); \
    const float rv14 = ush2f((unsigned short)c3_[2]) + ush2f((unsigned short)c3_[6]); \
    const float rv15 = ush2f((unsigned short)c3_[3]) + ush2f((unsigned short)c3_[7]); \
    REP16A(EDG_O) }
    REP8A(EDGE_K)
#undef EDGE_K
#undef EDG_O
#undef EDG_BODY

    // ---- mean-pool (tree reduce in sbuf, stride 17 = conflict-free) ----
    __syncthreads();   // all waves done with their S panels
    float* pool = sbuf;
#define NMS(i) pool[t * 17 + i] = nm##i;
    REP16A(NMS)
#undef NMS
    __syncthreads();
    for (int s = 128; s > 0; s >>= 1) {
        if (t < s) {
            #pragma unroll
            for (int i = 0; i < NH; ++i) pool[t * 17 + i] += pool[(t + s) * 17 + i];
        }
        __syncthreads();
    }

    // ---- head MLP + sigmoid ----
    if (t == 0) {
        float o1_0,o1_1,o1_2,o1_3,o1_4,o1_5,o1_6,o1_7;
#define HD_BODY(i) s = fmaf(wor[i], pool[i] * (1.f / NP), s);
#define HD_O(o) { const float* wor = &sWo1[(o) * NH]; float s = sbo1[o]; REP16B(HD_BODY) o1_##o = elu_f(s); }
        REP8A(HD_O)
#undef HD_O
#undef HD_BODY
        float o2 = sbo2v[0];
        o2 = fmaf(sWo2[0], o1_0, o2); o2 = fmaf(sWo2[1], o1_1, o2);
        o2 = fmaf(sWo2[2], o1_2, o2); o2 = fmaf(sWo2[3], o1_3, o2);
        o2 = fmaf(sWo2[4], o1_4, o2); o2 = fmaf(sWo2[5], o1_5, o2);
        o2 = fmaf(sWo2[6], o1_6, o2); o2 = fmaf(sWo2[7], o1_7, o2);
        gout[b] = 1.f / (1.f + expf(-o2));
    }
}

extern "C" void kernel_launch(void* const* d_in, const int* in_sizes, int n_in,
                              void* d_out, int out_size, void* d_ws, size_t ws_size,
                              hipStream_t stream) {
    const float* x   = (const float*)d_in[0];
    const float* W1  = (const float*)d_in[1];
    const float* W2  = (const float*)d_in[2];
    const float* b2  = (const float*)d_in[3];
    const float* W3  = (const float*)d_in[4];
    const float* b3  = (const float*)d_in[5];
    const float* We  = (const float*)d_in[6];
    const float* be  = (const float*)d_in[7];
    const float* Wo1 = (const float*)d_in[8];
    const float* bo1 = (const float*)d_in[9];
    const float* Wo2 = (const float*)d_in[10];
    const float* bo2 = (const float*)d_in[11];
    float* out = (float*)d_out;

    hipLaunchKernelGGL(edgenet_kernel, dim3(NB), dim3(NP), 0, stream,
                       x, W1, W2, b2, W3, b3, We, be, Wo1, bo1, Wo2, bo2, out);
}

// Round 6
// 165.233 us; speedup vs baseline: 3.2463x; 1.1684x over previous
//
#include <hip/hip_runtime.h>
#include <math.h>

#define NB 1024
#define NP 256
#define FIN 8
#define NH 16
#define NK 8

#define REP8A(X)  X(0) X(1) X(2) X(3) X(4) X(5) X(6) X(7)
#define REP16A(X) X(0) X(1) X(2) X(3) X(4) X(5) X(6) X(7) X(8) X(9) X(10) X(11) X(12) X(13) X(14) X(15)
#define REP16B(X) X(0) X(1) X(2) X(3) X(4) X(5) X(6) X(7) X(8) X(9) X(10) X(11) X(12) X(13) X(14) X(15)

typedef short s8v __attribute__((ext_vector_type(8)));
typedef float f4v __attribute__((ext_vector_type(4)));
typedef unsigned int u4v __attribute__((ext_vector_type(4)));

__device__ __forceinline__ float elu_f(float v) {
    return v > 0.f ? v : (__expf(v) - 1.f);
}
__device__ __forceinline__ unsigned bf16r(float f) {   // round-to-nearest-even bf16 bits
    unsigned u = __float_as_uint(f);
    return (u + 0x7FFFu + ((u >> 16) & 1u)) >> 16;
}
__device__ __forceinline__ float ush2f(unsigned short u) {
    return __uint_as_float(((unsigned)u) << 16);
}

// compare-exchange on packed float keys (exact)
#define CE(a, b) { float lo_ = fminf(a, b), hi_ = fmaxf(a, b); a = lo_; b = hi_; }
// Batcher odd-even mergesort, 8 elements, 19 CE
#define SORT8(x0,x1,x2,x3,x4,x5,x6,x7) \
    CE(x0,x1) CE(x2,x3) CE(x4,x5) CE(x6,x7) \
    CE(x0,x2) CE(x1,x3) CE(x4,x6) CE(x5,x7) \
    CE(x1,x2) CE(x5,x6) \
    CE(x0,x4) CE(x1,x5) CE(x2,x6) CE(x3,x7) \
    CE(x2,x4) CE(x3,x5) \
    CE(x1,x2) CE(x3,x4) CE(x5,x6)
// merge sorted-asc x0..x7 into running sorted-asc R0..R7, keep lowest 8:
// bitonic first stage (8 min) + 12-CE bitonic cleaner
#define MERGE8(x0,x1,x2,x3,x4,x5,x6,x7) \
    R0 = fminf(R0, x7); R1 = fminf(R1, x6); R2 = fminf(R2, x5); R3 = fminf(R3, x4); \
    R4 = fminf(R4, x3); R5 = fminf(R5, x2); R6 = fminf(R6, x1); R7 = fminf(R7, x0); \
    CE(R0,R4) CE(R1,R5) CE(R2,R6) CE(R3,R7) \
    CE(R0,R2) CE(R1,R3) CE(R4,R6) CE(R5,R7) \
    CE(R0,R1) CE(R2,R3) CE(R4,R5) CE(R6,R7)

__global__ __attribute__((amdgpu_flat_work_group_size(256, 256),
                          amdgpu_waves_per_eu(2, 4)))
void edgenet_kernel(
    const float* __restrict__ gx,
    const float* __restrict__ gW1, const float* __restrict__ gW2, const float* __restrict__ gb2,
    const float* __restrict__ gW3, const float* __restrict__ gb3,
    const float* __restrict__ gWe, const float* __restrict__ gbe,
    const float* __restrict__ gWo1, const float* __restrict__ gbo1,
    const float* __restrict__ gWo2, const float* __restrict__ gbo2,
    float* __restrict__ gout)
{
    const int b  = blockIdx.x;
    const int t  = threadIdx.x;
    const int w  = t >> 6;          // wave id (0..3)
    const int lq = (t >> 4) & 3;    // lane k-group
    const int lc = t & 15;          // lane row/col-in-tile

    // ---- LDS ----
    // sWbc: [0..256) = We[:,16:32]; [256..512) = We[:,0:16]-We[:,16:32].
    // After the post-PACKQ barrier both are dead -> reused as jidx (256 x uint2).
    __shared__ __align__(16) float sWbc[512];
    __shared__ float sbe[16];
    __shared__ float sWo1[128], sbo1[8], sWo2[8], sbo2v[1];
    // split-bf16 store: chunk (tile,q,c) = [hi(4q..4q+3)|lo(4q..4q+3)] of particle 16*tile+c
    __shared__ __align__(16) unsigned short hF[16][4][136];
    __shared__ float sqarr[256];
    // overlays: encoder weights -> per-wave S panels [4][64][18] -> per-wave base rows [64][17]
    __shared__ __align__(16) float sbuf[4608];
    __shared__ float spool[64];
    float* enc = sbuf;

    // ---- weight staging ----
    {
        int o = t >> 4, i = t & 15;
        float aa = gWe[o * 32 + i];
        float cc = gWe[o * 32 + 16 + i];
        sWbc[t] = cc;              // We_b
        sWbc[256 + t] = aa - cc;   // We_c
    }
    if (t < 128) { enc[t] = gW1[t]; sWo1[t] = gWo1[t]; }
    enc[128 + t] = gW2[t];
    enc[384 + t] = gW3[t];
    if (t < 16) { sbe[t] = gbe[t]; enc[640 + t] = gb2[t]; enc[656 + t] = gb3[t]; }
    if (t < 8)  { sbo1[t] = gbo1[t]; sWo2[t] = gWo2[t]; }
    if (t == 0) sbo2v[0] = gbo2[0];

    // ---- load particle ----
    float xi0, xi1, xi2, xi3, xi4, xi5, xi6, xi7;
    {
        const float4* xr = reinterpret_cast<const float4*>(gx + (size_t)b * (NP * FIN) + t * FIN);
        float4 v0 = xr[0], v1 = xr[1];
        xi0 = v0.x; xi1 = v0.y; xi2 = v0.z; xi3 = v0.w;
        xi4 = v1.x; xi5 = v1.y; xi6 = v1.z; xi7 = v1.w;
    }
    __syncthreads();

    // ---- encoder MLP 8->16->16->16 ----
    float l1_0,l1_1,l1_2,l1_3,l1_4,l1_5,l1_6,l1_7,l1_8,l1_9,l1_10,l1_11,l1_12,l1_13,l1_14,l1_15;
    float l2_0,l2_1,l2_2,l2_3,l2_4,l2_5,l2_6,l2_7,l2_8,l2_9,l2_10,l2_11,l2_12,l2_13,l2_14,l2_15;
    float hp0,hp1,hp2,hp3,hp4,hp5,hp6,hp7,hp8,hp9,hp10,hp11,hp12,hp13,hp14,hp15;

#define L1_BODY(i) s = fmaf(w1r[i], xi##i, s);
#define L1_O(o) { const float* w1r = &enc[(o) * FIN]; float s = 0.f; REP8A(L1_BODY) l1_##o = elu_f(s); }
    REP16A(L1_O)
#undef L1_O
#define L2_BODY(i) s = fmaf(w2r[i], l1_##i, s);
#define L2_O(o) { const float* w2r = &enc[128 + (o) * NH]; float s = enc[640 + (o)]; REP16B(L2_BODY) l2_##o = elu_f(s); }
    REP16A(L2_O)
#undef L2_O
#define L3_BODY(i) s = fmaf(w3r[i], l2_##i, s);
#define L3_O(o) { const float* w3r = &enc[384 + (o) * NH]; float s = enc[656 + (o)]; REP16B(L3_BODY) hp##o = elu_f(s); }
    REP16A(L3_O)
#undef L3_O

    // ---- base = be + We_c . hp  (xi-dependent half of edge MLP), pre-barrier ----
    float base0,base1,base2,base3,base4,base5,base6,base7,
          base8,base9,base10,base11,base12,base13,base14,base15;
#define BAS_BODY(i) s = fmaf(wcr[i], hp##i, s);
#define BAS_O(o) { const float* wcr = &sWbc[256 + (o) * NH]; float s = sbe[o]; REP16B(BAS_BODY) base##o = s; }
    REP16A(BAS_O)
#undef BAS_O
#undef BAS_BODY

    // ---- B-fragment for edge MFMA (split We_b), pre-barrier ----
    // lane (col=lc, group=lq): positions 8lq+i = Whi[lc][4lq+i], 8lq+4+i = Wlo[lc][4lq+i]
    s8v eB1;
    {
        float wv0 = sWbc[lc * 16 + 4 * lq + 0];
        float wv1 = sWbc[lc * 16 + 4 * lq + 1];
        float wv2 = sWbc[lc * 16 + 4 * lq + 2];
        float wv3 = sWbc[lc * 16 + 4 * lq + 3];
        unsigned h0 = bf16r(wv0), h1 = bf16r(wv1), h2 = bf16r(wv2), h3 = bf16r(wv3);
        unsigned g0 = bf16r(wv0 - ush2f((unsigned short)h0));
        unsigned g1 = bf16r(wv1 - ush2f((unsigned short)h1));
        unsigned g2 = bf16r(wv2 - ush2f((unsigned short)h2));
        unsigned g3 = bf16r(wv3 - ush2f((unsigned short)h3));
        eB1 = (s8v){(short)h0, (short)h1, (short)h2, (short)h3,
                    (short)g0, (short)g1, (short)g2, (short)g3};
    }

    float sqp = 0.f;
#define SQ_I(i) sqp = fmaf(hp##i, hp##i, sqp);
    REP16A(SQ_I)
#undef SQ_I

    // ---- bf16 hi/lo split of hp, store fragment-native ----
#define PACKQ(q, A, B, C, D) { \
    unsigned ha = bf16r(hp##A), hb = bf16r(hp##B), hc = bf16r(hp##C), hd = bf16r(hp##D); \
    float ra = hp##A - ush2f((unsigned short)ha); \
    float rb = hp##B - ush2f((unsigned short)hb); \
    float rc = hp##C - ush2f((unsigned short)hc); \
    float rd = hp##D - ush2f((unsigned short)hd); \
    unsigned la = bf16r(ra), lb = bf16r(rb), lcc = bf16r(rc), ld = bf16r(rd); \
    u4v pk; pk.x = ha | (hb << 16); pk.y = hc | (hd << 16); \
            pk.z = la | (lb << 16); pk.w = lcc | (ld << 16); \
    *(u4v*)&hF[t >> 4][q][(t & 15) * 8] = pk; }
    PACKQ(0, 0, 1, 2, 3)
    PACKQ(1, 4, 5, 6, 7)
    PACKQ(2, 8, 9, 10, 11)
    PACKQ(3, 12, 13, 14, 15)
#undef PACKQ
    sqarr[t] = sqp;
    __syncthreads();   // release point: hF/sqarr valid; sWbc becomes reusable

    // ---- hoisted A-fragments for Gram: wave w owns rows 64w..64w+63 ----
    const s8v af0 = *(const s8v*)&hF[4 * w + 0][lq][lc * 8];
    const s8v af1 = *(const s8v*)&hF[4 * w + 1][lq][lc * 8];
    const s8v af2 = *(const s8v*)&hF[4 * w + 2][lq][lc * 8];
    const s8v af3 = *(const s8v*)&hF[4 * w + 3][lq][lc * 8];

    // ---- kNN: MFMA Gram panels + sorting-network top-8 ----
    float R0, R1, R2, R3, R4, R5, R6, R7;
    R0=R1=R2=R3=R4=R5=R6=R7 = __uint_as_float(0x7F7FFFFFu);

    const int rr = t & 63;
    float* srow = &sbuf[w * 1152 + rr * 18];
    float* swr  = &sbuf[w * 1152 + lc];

    for (int jt = 0; jt < 16; ++jt) {
        const s8v bf1 = *(const s8v*)&hF[jt][lq][lc * 8];
        const s8v bf2 = __builtin_shufflevector(bf1, bf1, 4, 5, 6, 7, 0, 1, 2, 3);
        f4v z = {0.f, 0.f, 0.f, 0.f};
        f4v ac0 = __builtin_amdgcn_mfma_f32_16x16x32_bf16(af0, bf1, z, 0, 0, 0);
        ac0     = __builtin_amdgcn_mfma_f32_16x16x32_bf16(af0, bf2, ac0, 0, 0, 0);
        f4v ac1 = __builtin_amdgcn_mfma_f32_16x16x32_bf16(af1, bf1, z, 0, 0, 0);
        ac1     = __builtin_amdgcn_mfma_f32_16x16x32_bf16(af1, bf2, ac1, 0, 0, 0);
        f4v ac2 = __builtin_amdgcn_mfma_f32_16x16x32_bf16(af2, bf1, z, 0, 0, 0);
        ac2     = __builtin_amdgcn_mfma_f32_16x16x32_bf16(af2, bf2, ac2, 0, 0, 0);
        f4v ac3 = __builtin_amdgcn_mfma_f32_16x16x32_bf16(af3, bf1, z, 0, 0, 0);
        ac3     = __builtin_amdgcn_mfma_f32_16x16x32_bf16(af3, bf2, ac3, 0, 0, 0);

        // scatter S tiles to this wave's panel (row = 4*lq + r per m89)
#define WS(tt, r) swr[(16 * (tt) + 4 * lq + (r)) * 18] = ac##tt[r];
        WS(0,0) WS(0,1) WS(0,2) WS(0,3)
        WS(1,0) WS(1,1) WS(1,2) WS(1,3)
        WS(2,0) WS(2,1) WS(2,2) WS(2,3)
        WS(3,0) WS(3,1) WS(3,2) WS(3,3)
#undef WS

        const float4 sqA = *(const float4*)&sqarr[16 * jt + 0];
        const float4 sqB = *(const float4*)&sqarr[16 * jt + 4];
        const float4 sqC = *(const float4*)&sqarr[16 * jt + 8];
        const float4 sqD = *(const float4*)&sqarr[16 * jt + 12];
        const float2 p0 = *(const float2*)&srow[0],  p1 = *(const float2*)&srow[2];
        const float2 p2 = *(const float2*)&srow[4],  p3 = *(const float2*)&srow[6];
        const float2 p4 = *(const float2*)&srow[8],  p5 = *(const float2*)&srow[10];
        const float2 p6 = *(const float2*)&srow[12], p7 = *(const float2*)&srow[14];
        const int jt16 = jt * 16;

#define KEY(c, sv, sqc) __uint_as_float((__float_as_uint(fmaf(-2.f, (sv), sqp + (sqc))) & 0xFFFFFF00u) | (unsigned)(jt16 + (c)))
        float k0  = KEY(0,  p0.x, sqA.x), k1  = KEY(1,  p0.y, sqA.y);
        float k2  = KEY(2,  p1.x, sqA.z), k3  = KEY(3,  p1.y, sqA.w);
        float k4  = KEY(4,  p2.x, sqB.x), k5  = KEY(5,  p2.y, sqB.y);
        float k6  = KEY(6,  p3.x, sqB.z), k7  = KEY(7,  p3.y, sqB.w);
        float k8  = KEY(8,  p4.x, sqC.x), k9  = KEY(9,  p4.y, sqC.y);
        float k10 = KEY(10, p5.x, sqC.z), k11 = KEY(11, p5.y, sqC.w);
        float k12 = KEY(12, p6.x, sqD.x), k13 = KEY(13, p6.y, sqD.y);
        float k14 = KEY(14, p7.x, sqD.z), k15 = KEY(15, p7.y, sqD.w);
#undef KEY
        SORT8(k0, k1, k2, k3, k4, k5, k6, k7)
        SORT8(k8, k9, k10, k11, k12, k13, k14, k15)
        MERGE8(k0, k1, k2, k3, k4, k5, k6, k7)
        MERGE8(k8, k9, k10, k11, k12, k13, k14, k15)
    }

    // ---- pack neighbor indices, publish to jidx (overlays dead sWbc) ----
    {
        unsigned idxlo = (__float_as_uint(R0) & 0xFFu)
                       | ((__float_as_uint(R1) & 0xFFu) << 8)
                       | ((__float_as_uint(R2) & 0xFFu) << 16)
                       | ((__float_as_uint(R3) & 0xFFu) << 24);
        unsigned idxhi = (__float_as_uint(R4) & 0xFFu)
                       | ((__float_as_uint(R5) & 0xFFu) << 8)
                       | ((__float_as_uint(R6) & 0xFFu) << 16)
                       | ((__float_as_uint(R7) & 0xFFu) << 24);
        ((uint2*)sWbc)[t] = make_uint2(idxlo, idxhi);   // own-wave readers only
    }

    // ---- stash base rows into this wave's (now dead) panel region ----
    {
        float* sb = &sbuf[w * 1152 + (t & 63) * 17];
#define SBW(i) sb[i] = base##i;
        REP16A(SBW)
#undef SBW
    }

    // ---- edge MLP via MFMA + max-then-ELU + in-register pool ----
    float psum = 0.f;
    {
        const s8v eB2 = __builtin_shufflevector(eB1, eB1, 4, 5, 6, 7, 0, 1, 2, 3);
        const uint2* jidxp = (const uint2*)sWbc;
        const float* sbase = &sbuf[w * 1152];
        const int erow = lc;            // A-row within tile = edge index 0..15
        #pragma unroll 4
        for (int tt = 0; tt < 32; ++tt) {
            uint2 jv = jidxp[64 * w + 2 * tt + (erow >> 3)];
            unsigned word = (erow & 4) ? jv.y : jv.x;
            int jp = (int)((word >> ((erow & 3) * 8)) & 0xFFu);
            const s8v av = *(const s8v*)&hF[jp >> 4][lq][(jp & 15) * 8];
            f4v z = {0.f, 0.f, 0.f, 0.f};
            f4v d1 = __builtin_amdgcn_mfma_f32_16x16x32_bf16(av, eB1, z, 0, 0, 0);
            d1     = __builtin_amdgcn_mfma_f32_16x16x32_bf16(av, eB2, d1, 0, 0, 0);
            // lane holds rows 4*lq..4*lq+3 (one particle's 4 k's); pair with lq^1
            float mx = fmaxf(fmaxf(d1[0], d1[1]), fmaxf(d1[2], d1[3]));
            mx = fmaxf(mx, __shfl_xor(mx, 16, 64));
            float bz = sbase[(2 * tt + (lq >> 1)) * 17 + lc];
            psum += elu_f(mx + bz);     // each (p,col) contributed by exactly 2 lanes
        }
    }
    psum += __shfl_xor(psum, 16, 64);
    psum += __shfl_xor(psum, 32, 64);
    if ((t & 63) < 16) spool[(w << 4) + lc] = psum;   // = 2 * sum_p node[p][lc] over wave
    __syncthreads();

    // ---- head MLP + sigmoid ----
    if (t == 0) {
#define PL(i) const float pl##i = (spool[i] + spool[16 + i] + spool[32 + i] + spool[48 + i]) * (1.f / 512.f);
        REP16A(PL)
#undef PL
        float o1_0,o1_1,o1_2,o1_3,o1_4,o1_5,o1_6,o1_7;
#define HD_BODY(i) s = fmaf(wor[i], pl##i, s);
#define HD_O(o) { const float* wor = &sWo1[(o) * NH]; float s = sbo1[o]; REP16B(HD_BODY) o1_##o = elu_f(s); }
        REP8A(HD_O)
#undef HD_O
#undef HD_BODY
        float o2 = sbo2v[0];
        o2 = fmaf(sWo2[0], o1_0, o2); o2 = fmaf(sWo2[1], o1_1, o2);
        o2 = fmaf(sWo2[2], o1_2, o2); o2 = fmaf(sWo2[3], o1_3, o2);
        o2 = fmaf(sWo2[4], o1_4, o2); o2 = fmaf(sWo2[5], o1_5, o2);
        o2 = fmaf(sWo2[6], o1_6, o2); o2 = fmaf(sWo2[7], o1_7, o2);
        gout[b] = 1.f / (1.f + expf(-o2));
    }
}

extern "C" void kernel_launch(void* const* d_in, const int* in_sizes, int n_in,
                              void* d_out, int out_size, void* d_ws, size_t ws_size,
                              hipStream_t stream) {
    const float* x   = (const float*)d_in[0];
    const float* W1  = (const float*)d_in[1];
    const float* W2  = (const float*)d_in[2];
    const float* b2  = (const float*)d_in[3];
    const float* W3  = (const float*)d_in[4];
    const float* b3  = (const float*)d_in[5];
    const float* We  = (const float*)d_in[6];
    const float* be  = (const float*)d_in[7];
    const float* Wo1 = (const float*)d_in[8];
    const float* bo1 = (const float*)d_in[9];
    const float* Wo2 = (const float*)d_in[10];
    const float* bo2 = (const float*)d_in[11];
    float* out = (float*)d_out;

    hipLaunchKernelGGL(edgenet_kernel, dim3(NB), dim3(NP), 0, stream,
                       x, W1, W2, b2, W3, b3, We, be, Wo1, bo1, Wo2, bo2, out);
}

// Round 9
// 143.646 us; speedup vs baseline: 3.7341x; 1.1503x over previous
//
#include <hip/hip_runtime.h>
#include <math.h>

#define NB 1024
#define NP 256
#define FIN 8
#define NH 16
#define NK 8

#define REP8A(X)  X(0) X(1) X(2) X(3) X(4) X(5) X(6) X(7)
#define REP16A(X) X(0) X(1) X(2) X(3) X(4) X(5) X(6) X(7) X(8) X(9) X(10) X(11) X(12) X(13) X(14) X(15)
#define REP16B(X) X(0) X(1) X(2) X(3) X(4) X(5) X(6) X(7) X(8) X(9) X(10) X(11) X(12) X(13) X(14) X(15)

typedef short s8v __attribute__((ext_vector_type(8)));
typedef float f4v __attribute__((ext_vector_type(4)));
typedef unsigned int u4v __attribute__((ext_vector_type(4)));

__device__ __forceinline__ float elu_f(float v) {
    return v > 0.f ? v : (__expf(v) - 1.f);
}
__device__ __forceinline__ unsigned bf16r(float f) {   // round-to-nearest-even bf16 bits
    unsigned u = __float_as_uint(f);
    return (u + 0x7FFFu + ((u >> 16) & 1u)) >> 16;
}
__device__ __forceinline__ float ush2f(unsigned short u) {
    return __uint_as_float(((unsigned)u) << 16);
}

// compare-exchange on packed float keys (exact)
#define CE(a, b) { float lo_ = fminf(a, b), hi_ = fmaxf(a, b); a = lo_; b = hi_; }
// Batcher odd-even mergesort, 8 elements, 19 CE
#define SORT8(x0,x1,x2,x3,x4,x5,x6,x7) \
    CE(x0,x1) CE(x2,x3) CE(x4,x5) CE(x6,x7) \
    CE(x0,x2) CE(x1,x3) CE(x4,x6) CE(x5,x7) \
    CE(x1,x2) CE(x5,x6) \
    CE(x0,x4) CE(x1,x5) CE(x2,x6) CE(x3,x7) \
    CE(x2,x4) CE(x3,x5) \
    CE(x1,x2) CE(x3,x4) CE(x5,x6)
// merge sorted-asc x0..x7 into running sorted-asc R0..R7, keep lowest 8
#define MERGE8(x0,x1,x2,x3,x4,x5,x6,x7) \
    R0 = fminf(R0, x7); R1 = fminf(R1, x6); R2 = fminf(R2, x5); R3 = fminf(R3, x4); \
    R4 = fminf(R4, x3); R5 = fminf(R5, x2); R6 = fminf(R6, x1); R7 = fminf(R7, x0); \
    CE(R0,R4) CE(R1,R5) CE(R2,R6) CE(R3,R7) \
    CE(R0,R2) CE(R1,R3) CE(R4,R6) CE(R5,R7) \
    CE(R0,R1) CE(R2,R3) CE(R4,R5) CE(R6,R7)

__global__ __attribute__((amdgpu_flat_work_group_size(256, 256),
                          amdgpu_waves_per_eu(2, 4)))
void edgenet_kernel(
    const float* __restrict__ gx,
    const float* __restrict__ gW1, const float* __restrict__ gW2, const float* __restrict__ gb2,
    const float* __restrict__ gW3, const float* __restrict__ gb3,
    const float* __restrict__ gWe, const float* __restrict__ gbe,
    const float* __restrict__ gWo1, const float* __restrict__ gbo1,
    const float* __restrict__ gWo2, const float* __restrict__ gbo2,
    float* __restrict__ gout)
{
    const int b  = blockIdx.x;
    const int t  = threadIdx.x;
    const int w  = t >> 6;          // wave id (0..3)
    const int lq = (t >> 4) & 3;    // lane k-group
    const int lc = t & 15;          // lane row/col-in-tile

    // ---- LDS (38.3 KB total -> 4 blocks/CU) ----
    // split-bf16 store: chunk (tile,q,c) = [hi(4q..4q+3)|lo(4q..4q+3)] of particle 16*tile+c
    __shared__ __align__(16) unsigned short hF[16][4][136];
    __shared__ __align__(16) float sq2arr[256];          // 0.5*||h||^2
    // per-wave transposed Gram panel [64 own particles][16 cands + 4 pad];
    // after the jt loop the region is reused: base rows (stride 17) + packed jidx
    __shared__ __align__(16) float spanel[4][64][20];
    __shared__ float spool[64];

    // ---- load particle (no weight staging: weights read via uniform s_loads) ----
    float xi0, xi1, xi2, xi3, xi4, xi5, xi6, xi7;
    {
        const float4* xr = reinterpret_cast<const float4*>(gx + (size_t)b * (NP * FIN) + t * FIN);
        float4 v0 = xr[0], v1 = xr[1];
        xi0 = v0.x; xi1 = v0.y; xi2 = v0.z; xi3 = v0.w;
        xi4 = v1.x; xi5 = v1.y; xi6 = v1.z; xi7 = v1.w;
    }

    // ---- encoder MLP 8->16->16->16 (weights direct from global, uniform) ----
    float l1_0,l1_1,l1_2,l1_3,l1_4,l1_5,l1_6,l1_7,l1_8,l1_9,l1_10,l1_11,l1_12,l1_13,l1_14,l1_15;
    float l2_0,l2_1,l2_2,l2_3,l2_4,l2_5,l2_6,l2_7,l2_8,l2_9,l2_10,l2_11,l2_12,l2_13,l2_14,l2_15;
    float hp0,hp1,hp2,hp3,hp4,hp5,hp6,hp7,hp8,hp9,hp10,hp11,hp12,hp13,hp14,hp15;

#define L1_BODY(i) s = fmaf(gW1[(o_) * FIN + i], xi##i, s);
#define L1_O(o) { const int o_ = (o); float s = 0.f; REP8A(L1_BODY) l1_##o = elu_f(s); }
    REP16A(L1_O)
#undef L1_O
#undef L1_BODY
#define L2_BODY(i) s = fmaf(gW2[(o_) * NH + i], l1_##i, s);
#define L2_O(o) { const int o_ = (o); float s = gb2[o_]; REP16B(L2_BODY) l2_##o = elu_f(s); }
    REP16A(L2_O)
#undef L2_O
#undef L2_BODY
#define L3_BODY(i) s = fmaf(gW3[(o_) * NH + i], l2_##i, s);
#define L3_O(o) { const int o_ = (o); float s = gb3[o_]; REP16B(L3_BODY) hp##o = elu_f(s); }
    REP16A(L3_O)
#undef L3_O
#undef L3_BODY

    // ---- base = be + (We_a - We_b) . hp  (uniform weight reads) ----
    float base0,base1,base2,base3,base4,base5,base6,base7,
          base8,base9,base10,base11,base12,base13,base14,base15;
#define BAS_BODY(i) s = fmaf(gWe[(o_) * 32 + i] - gWe[(o_) * 32 + 16 + i], hp##i, s);
#define BAS_O(o) { const int o_ = (o); float s = gbe[o_]; REP16B(BAS_BODY) base##o = s; }
    REP16A(BAS_O)
#undef BAS_O
#undef BAS_BODY

    // ---- B-fragment for edge MFMA: split of We_b = We[:,16:32] (per-lane global float4) ----
    s8v eB1;
    {
        float4 wv = *reinterpret_cast<const float4*>(gWe + lc * 32 + 16 + 4 * lq);
        unsigned h0 = bf16r(wv.x), h1 = bf16r(wv.y), h2 = bf16r(wv.z), h3 = bf16r(wv.w);
        unsigned g0 = bf16r(wv.x - ush2f((unsigned short)h0));
        unsigned g1 = bf16r(wv.y - ush2f((unsigned short)h1));
        unsigned g2 = bf16r(wv.z - ush2f((unsigned short)h2));
        unsigned g3 = bf16r(wv.w - ush2f((unsigned short)h3));
        eB1 = (s8v){(short)h0, (short)h1, (short)h2, (short)h3,
                    (short)g0, (short)g1, (short)g2, (short)g3};
    }

    float sqp = 0.f;
#define SQ_I(i) sqp = fmaf(hp##i, hp##i, sqp);
    REP16A(SQ_I)
#undef SQ_I
    const float sqp2 = 0.5f * sqp;

    // ---- bf16 hi/lo split of hp, store fragment-native ----
#define PACKQ(q, A, B, C, D) { \
    unsigned ha = bf16r(hp##A), hb = bf16r(hp##B), hc = bf16r(hp##C), hd = bf16r(hp##D); \
    float ra = hp##A - ush2f((unsigned short)ha); \
    float rb = hp##B - ush2f((unsigned short)hb); \
    float rc = hp##C - ush2f((unsigned short)hc); \
    float rd = hp##D - ush2f((unsigned short)hd); \
    unsigned la = bf16r(ra), lb = bf16r(rb), lcc = bf16r(rc), ld = bf16r(rd); \
    u4v pk; pk.x = ha | (hb << 16); pk.y = hc | (hd << 16); \
            pk.z = la | (lb << 16); pk.w = lcc | (ld << 16); \
    *(u4v*)&hF[t >> 4][q][(t & 15) * 8] = pk; }
    PACKQ(0, 0, 1, 2, 3)
    PACKQ(1, 4, 5, 6, 7)
    PACKQ(2, 8, 9, 10, 11)
    PACKQ(3, 12, 13, 14, 15)
#undef PACKQ
    sq2arr[t] = sqp2;
    __syncthreads();   // hF / sq2arr valid block-wide

    // ---- own-particle fragments (B-side of transposed Gram) ----
    const s8v af0 = *(const s8v*)&hF[4 * w + 0][lq][lc * 8];
    const s8v af1 = *(const s8v*)&hF[4 * w + 1][lq][lc * 8];
    const s8v af2 = *(const s8v*)&hF[4 * w + 2][lq][lc * 8];
    const s8v af3 = *(const s8v*)&hF[4 * w + 3][lq][lc * 8];

    // ---- kNN: transposed MFMA Gram + sorting-network top-8 ----
    // mfma(bf_jt, af_tt): D[row=cand 4lq+r][col=own lc]; writer lane owns 4
    // contiguous candidates of particle 16tt+lc -> b128 panel write of
    // (sq2[cand] - S); reader reads its 16 cands as 4 b128.
    float R0, R1, R2, R3, R4, R5, R6, R7;
    R0=R1=R2=R3=R4=R5=R6=R7 = __uint_as_float(0x7F7FFFFFu);

    for (int jt = 0; jt < 16; ++jt) {
        const s8v bf1 = *(const s8v*)&hF[jt][lq][lc * 8];
        const s8v bf2 = __builtin_shufflevector(bf1, bf1, 4, 5, 6, 7, 0, 1, 2, 3);
        const float4 sqv = *(const float4*)&sq2arr[16 * jt + 4 * lq];
        f4v z = {0.f, 0.f, 0.f, 0.f};
#define GRAM_T(tt) { \
        f4v ac = __builtin_amdgcn_mfma_f32_16x16x32_bf16(bf1, af##tt, z, 0, 0, 0); \
        ac     = __builtin_amdgcn_mfma_f32_16x16x32_bf16(bf2, af##tt, ac, 0, 0, 0); \
        float4 ov; ov.x = sqv.x - ac[0]; ov.y = sqv.y - ac[1]; \
                   ov.z = sqv.z - ac[2]; ov.w = sqv.w - ac[3]; \
        *(float4*)&spanel[w][16 * (tt) + lc][4 * lq] = ov; }
        GRAM_T(0) GRAM_T(1) GRAM_T(2) GRAM_T(3)
#undef GRAM_T

        // same-wave write->read: in-order LDS pipe, no barrier needed
        const float4* pr = (const float4*)&spanel[w][t & 63][0];
        const float4 q0 = pr[0], q1 = pr[1], q2 = pr[2], q3 = pr[3];
        const int jt16 = jt * 16;
#define KEY(c, val) __uint_as_float((__float_as_uint((val) + sqp2) & 0xFFFFFF00u) | (unsigned)(jt16 + (c)))
        float k0  = KEY(0,  q0.x), k1  = KEY(1,  q0.y);
        float k2  = KEY(2,  q0.z), k3  = KEY(3,  q0.w);
        float k4  = KEY(4,  q1.x), k5  = KEY(5,  q1.y);
        float k6  = KEY(6,  q1.z), k7  = KEY(7,  q1.w);
        float k8  = KEY(8,  q2.x), k9  = KEY(9,  q2.y);
        float k10 = KEY(10, q2.z), k11 = KEY(11, q2.w);
        float k12 = KEY(12, q3.x), k13 = KEY(13, q3.y);
        float k14 = KEY(14, q3.z), k15 = KEY(15, q3.w);
#undef KEY
        SORT8(k0, k1, k2, k3, k4, k5, k6, k7)
        SORT8(k8, k9, k10, k11, k12, k13, k14, k15)
        MERGE8(k0, k1, k2, k3, k4, k5, k6, k7)
        MERGE8(k8, k9, k10, k11, k12, k13, k14, k15)
    }

    // ---- overlay region (panels dead, same-wave use only): base rows + jidx ----
    float* sbase = &spanel[w][0][0];                     // stride-17 rows
    uint2* jj    = (uint2*)(&spanel[w][0][0] + 1088);    // 64 uint2 per wave
    {
        unsigned idxlo = (__float_as_uint(R0) & 0xFFu)
                       | ((__float_as_uint(R1) & 0xFFu) << 8)
                       | ((__float_as_uint(R2) & 0xFFu) << 16)
                       | ((__float_as_uint(R3) & 0xFFu) << 24);
        unsigned idxhi = (__float_as_uint(R4) & 0xFFu)
                       | ((__float_as_uint(R5) & 0xFFu) << 8)
                       | ((__float_as_uint(R6) & 0xFFu) << 16)
                       | ((__float_as_uint(R7) & 0xFFu) << 24);
        jj[t & 63] = make_uint2(idxlo, idxhi);
    }
    {
        float* sb = sbase + (t & 63) * 17;
#define SBW(i) sb[i] = base##i;
        REP16A(SBW)
#undef SBW
    }

    // ---- edge MLP via MFMA + max-then-ELU + in-register pool ----
    float psum = 0.f;
    {
        const s8v eB2 = __builtin_shufflevector(eB1, eB1, 4, 5, 6, 7, 0, 1, 2, 3);
        const int erow = lc;            // A-row within tile = edge index 0..15
        #pragma unroll 4
        for (int tt = 0; tt < 32; ++tt) {
            uint2 jv = jj[2 * tt + (erow >> 3)];
            unsigned word = (erow & 4) ? jv.y : jv.x;
            int jp = (int)((word >> ((erow & 3) * 8)) & 0xFFu);
            const s8v av = *(const s8v*)&hF[jp >> 4][lq][(jp & 15) * 8];
            f4v z = {0.f, 0.f, 0.f, 0.f};
            f4v d1 = __builtin_amdgcn_mfma_f32_16x16x32_bf16(av, eB1, z, 0, 0, 0);
            d1     = __builtin_amdgcn_mfma_f32_16x16x32_bf16(av, eB2, d1, 0, 0, 0);
            // lane holds rows 4*lq..4*lq+3 (one particle's 4 k's); pair with lq^1
            float mx = fmaxf(fmaxf(d1[0], d1[1]), fmaxf(d1[2], d1[3]));
            mx = fmaxf(mx, __shfl_xor(mx, 16, 64));
            float bz = sbase[(2 * tt + (lq >> 1)) * 17 + lc];
            psum += elu_f(mx + bz);     // each (p,col) contributed by exactly 2 lanes
        }
    }
    psum += __shfl_xor(psum, 16, 64);
    psum += __shfl_xor(psum, 32, 64);
    if ((t & 63) < 16) spool[(w << 4) + lc] = psum;   // = 2 * sum_p node[p][lc] over wave
    __syncthreads();

    // ---- head MLP + sigmoid (weights direct from global) ----
    if (t == 0) {
#define PL(i) const float pl##i = (spool[i] + spool[16 + i] + spool[32 + i] + spool[48 + i]) * (1.f / 512.f);
        REP16A(PL)
#undef PL
        float o1_0,o1_1,o1_2,o1_3,o1_4,o1_5,o1_6,o1_7;
#define HD_BODY(i) s = fmaf(gWo1[(o_) * NH + i], pl##i, s);
#define HD_O(o) { const int o_ = (o); float s = gbo1[o_]; REP16B(HD_BODY) o1_##o = elu_f(s); }
        REP8A(HD_O)
#undef HD_O
#undef HD_BODY
        float o2 = gbo2[0];
        o2 = fmaf(gWo2[0], o1_0, o2); o2 = fmaf(gWo2[1], o1_1, o2);
        o2 = fmaf(gWo2[2], o1_2, o2); o2 = fmaf(gWo2[3], o1_3, o2);
        o2 = fmaf(gWo2[4], o1_4, o2); o2 = fmaf(gWo2[5], o1_5, o2);
        o2 = fmaf(gWo2[6], o1_6, o2); o2 = fmaf(gWo2[7], o1_7, o2);
        gout[b] = 1.f / (1.f + expf(-o2));
    }
}

extern "C" void kernel_launch(void* const* d_in, const int* in_sizes, int n_in,
                              void* d_out, int out_size, void* d_ws, size_t ws_size,
                              hipStream_t stream) {
    const float* x   = (const float*)d_in[0];
    const float* W1  = (const float*)d_in[1];
    const float* W2  = (const float*)d_in[2];
    const float* b2  = (const float*)d_in[3];
    const float* W3  = (const float*)d_in[4];
    const float* b3  = (const float*)d_in[5];
    const float* We  = (const float*)d_in[6];
    const float* be  = (const float*)d_in[7];
    const float* Wo1 = (const float*)d_in[8];
    const float* bo1 = (const float*)d_in[9];
    const float* Wo2 = (const float*)d_in[10];
    const float* bo2 = (const float*)d_in[11];
    float* out = (float*)d_out;

    hipLaunchKernelGGL(edgenet_kernel, dim3(NB), dim3(NP), 0, stream,
                       x, W1, W2, b2, W3, b3, We, be, Wo1, bo1, Wo2, bo2, out);
}

// Round 10
// 131.513 us; speedup vs baseline: 4.0786x; 1.0923x over previous
//
#include <hip/hip_runtime.h>
#include <math.h>

#define NB 1024
#define NP 256
#define FIN 8
#define NH 16
#define NK 8

#define REP8A(X)  X(0) X(1) X(2) X(3) X(4) X(5) X(6) X(7)
#define REP16A(X) X(0) X(1) X(2) X(3) X(4) X(5) X(6) X(7) X(8) X(9) X(10) X(11) X(12) X(13) X(14) X(15)
#define REP16B(X) X(0) X(1) X(2) X(3) X(4) X(5) X(6) X(7) X(8) X(9) X(10) X(11) X(12) X(13) X(14) X(15)

typedef short s8v __attribute__((ext_vector_type(8)));
typedef float f4v __attribute__((ext_vector_type(4)));
typedef unsigned int u4v __attribute__((ext_vector_type(4)));

__device__ __forceinline__ float elu_f(float v) {
    return v > 0.f ? v : (__expf(v) - 1.f);
}
__device__ __forceinline__ unsigned bf16r(float f) {   // round-to-nearest-even bf16 bits
    unsigned u = __float_as_uint(f);
    return (u + 0x7FFFu + ((u >> 16) & 1u)) >> 16;
}
__device__ __forceinline__ float ush2f(unsigned short u) {
    return __uint_as_float(((unsigned)u) << 16);
}

// compare-exchange on packed float keys (exact)
#define CE(a, b) { float lo_ = fminf(a, b), hi_ = fmaxf(a, b); a = lo_; b = hi_; }
// Batcher odd-even mergesort, 8 elements, 19 CE
#define SORT8(x0,x1,x2,x3,x4,x5,x6,x7) \
    CE(x0,x1) CE(x2,x3) CE(x4,x5) CE(x6,x7) \
    CE(x0,x2) CE(x1,x3) CE(x4,x6) CE(x5,x7) \
    CE(x1,x2) CE(x5,x6) \
    CE(x0,x4) CE(x1,x5) CE(x2,x6) CE(x3,x7) \
    CE(x2,x4) CE(x3,x5) \
    CE(x1,x2) CE(x3,x4) CE(x5,x6)
// merge sorted-asc x0..x7 into running sorted-asc R0..R7, keep lowest 8
#define MERGE8(x0,x1,x2,x3,x4,x5,x6,x7) \
    R0 = fminf(R0, x7); R1 = fminf(R1, x6); R2 = fminf(R2, x5); R3 = fminf(R3, x4); \
    R4 = fminf(R4, x3); R5 = fminf(R5, x2); R6 = fminf(R6, x1); R7 = fminf(R7, x0); \
    CE(R0,R4) CE(R1,R5) CE(R2,R6) CE(R3,R7) \
    CE(R0,R2) CE(R1,R3) CE(R4,R6) CE(R5,R7) \
    CE(R0,R1) CE(R2,R3) CE(R4,R5) CE(R6,R7)

#define KEYV(val, c) __uint_as_float((__float_as_uint((val) + sqp2) & 0xFFFFFF00u) | (unsigned)(c))

// Distributed top-8 for own-tile ttc: 4 lanes (lq=0..3, same lc) each scan
// their 4 D-rows/jt, keep sorted-8, then 2 shfl_xor bitonic merges converge
// all 4 lanes to the identical top-8 of all 256 candidates. No LDS panel.
#define KNN_TT(ttc) { \
    const s8v af = *(const s8v*)&hF[4 * w + (ttc)][lq][lc * 8]; \
    float R0, R1, R2, R3, R4, R5, R6, R7; \
    R0=R1=R2=R3=R4=R5=R6=R7 = __uint_as_float(0x7F7FFFFFu); \
    for (int jt2 = 0; jt2 < 8; ++jt2) { \
        const s8v b1a = *(const s8v*)&hF[2 * jt2][lq][lc * 8]; \
        const s8v b1b = *(const s8v*)&hF[2 * jt2 + 1][lq][lc * 8]; \
        const s8v b2a = __builtin_shufflevector(b1a, b1a, 4, 5, 6, 7, 0, 1, 2, 3); \
        const s8v b2b = __builtin_shufflevector(b1b, b1b, 4, 5, 6, 7, 0, 1, 2, 3); \
        const float4 sqa = *(const float4*)&sq2arr[32 * jt2 + 4 * lq]; \
        const float4 sqb = *(const float4*)&sq2arr[32 * jt2 + 16 + 4 * lq]; \
        f4v z = {0.f, 0.f, 0.f, 0.f}; \
        f4v a1 = __builtin_amdgcn_mfma_f32_16x16x32_bf16(b1a, af, z, 0, 0, 0); \
        f4v a2 = __builtin_amdgcn_mfma_f32_16x16x32_bf16(b2a, af, z, 0, 0, 0); \
        f4v a3 = __builtin_amdgcn_mfma_f32_16x16x32_bf16(b1b, af, z, 0, 0, 0); \
        f4v a4 = __builtin_amdgcn_mfma_f32_16x16x32_bf16(b2b, af, z, 0, 0, 0); \
        const int c0 = 32 * jt2 + 4 * lq, c1 = c0 + 16; \
        float k0 = KEYV(sqa.x - a1[0] - a2[0], c0 + 0); \
        float k1 = KEYV(sqa.y - a1[1] - a2[1], c0 + 1); \
        float k2 = KEYV(sqa.z - a1[2] - a2[2], c0 + 2); \
        float k3 = KEYV(sqa.w - a1[3] - a2[3], c0 + 3); \
        float k4 = KEYV(sqb.x - a3[0] - a4[0], c1 + 0); \
        float k5 = KEYV(sqb.y - a3[1] - a4[1], c1 + 1); \
        float k6 = KEYV(sqb.z - a3[2] - a4[2], c1 + 2); \
        float k7 = KEYV(sqb.w - a3[3] - a4[3], c1 + 3); \
        SORT8(k0, k1, k2, k3, k4, k5, k6, k7) \
        MERGE8(k0, k1, k2, k3, k4, k5, k6, k7) \
    } \
    { float o0 = __shfl_xor(R0, 16), o1 = __shfl_xor(R1, 16), \
            o2 = __shfl_xor(R2, 16), o3 = __shfl_xor(R3, 16), \
            o4 = __shfl_xor(R4, 16), o5 = __shfl_xor(R5, 16), \
            o6 = __shfl_xor(R6, 16), o7 = __shfl_xor(R7, 16); \
      MERGE8(o0, o1, o2, o3, o4, o5, o6, o7) } \
    { float o0 = __shfl_xor(R0, 32), o1 = __shfl_xor(R1, 32), \
            o2 = __shfl_xor(R2, 32), o3 = __shfl_xor(R3, 32), \
            o4 = __shfl_xor(R4, 32), o5 = __shfl_xor(R5, 32), \
            o6 = __shfl_xor(R6, 32), o7 = __shfl_xor(R7, 32); \
      MERGE8(o0, o1, o2, o3, o4, o5, o6, o7) } \
    if (lq == (ttc)) { \
        unsigned plo = (__float_as_uint(R0) & 0xFFu) \
                     | ((__float_as_uint(R1) & 0xFFu) << 8) \
                     | ((__float_as_uint(R2) & 0xFFu) << 16) \
                     | ((__float_as_uint(R3) & 0xFFu) << 24); \
        unsigned phi = (__float_as_uint(R4) & 0xFFu) \
                     | ((__float_as_uint(R5) & 0xFFu) << 8) \
                     | ((__float_as_uint(R6) & 0xFFu) << 16) \
                     | ((__float_as_uint(R7) & 0xFFu) << 24); \
        jjarr[w][16 * (ttc) + lc] = make_uint2(plo, phi); \
    } \
}

__global__ __attribute__((amdgpu_flat_work_group_size(256, 256),
                          amdgpu_waves_per_eu(2, 4)))
void edgenet_kernel(
    const float* __restrict__ gx,
    const float* __restrict__ gW1, const float* __restrict__ gW2, const float* __restrict__ gb2,
    const float* __restrict__ gW3, const float* __restrict__ gb3,
    const float* __restrict__ gWe, const float* __restrict__ gbe,
    const float* __restrict__ gWo1, const float* __restrict__ gbo1,
    const float* __restrict__ gWo2, const float* __restrict__ gbo2,
    float* __restrict__ gout)
{
    const int b  = blockIdx.x;
    const int t  = threadIdx.x;
    const int w  = t >> 6;          // wave id (0..3)
    const int lq = (t >> 4) & 3;    // lane k-group
    const int lc = t & 15;          // lane row/col-in-tile

    // ---- LDS (~38.1 KB -> 4 blocks/CU) ----
    __shared__ __align__(16) unsigned short hF[16][4][136];
    __shared__ __align__(16) float sq2arr[256];          // 0.5*||h||^2
    __shared__ __align__(16) float sbaseA[4][64][17];    // per-wave base rows
    __shared__ __align__(16) uint2 jjarr[4][64];         // per-wave packed neighbor idx
    __shared__ float spool[64];

    // ---- load particle ----
    float xi0, xi1, xi2, xi3, xi4, xi5, xi6, xi7;
    {
        const float4* xr = reinterpret_cast<const float4*>(gx + (size_t)b * (NP * FIN) + t * FIN);
        float4 v0 = xr[0], v1 = xr[1];
        xi0 = v0.x; xi1 = v0.y; xi2 = v0.z; xi3 = v0.w;
        xi4 = v1.x; xi5 = v1.y; xi6 = v1.z; xi7 = v1.w;
    }

    // ---- encoder MLP 8->16->16->16 (weights direct from global, uniform) ----
    float l1_0,l1_1,l1_2,l1_3,l1_4,l1_5,l1_6,l1_7,l1_8,l1_9,l1_10,l1_11,l1_12,l1_13,l1_14,l1_15;
    float l2_0,l2_1,l2_2,l2_3,l2_4,l2_5,l2_6,l2_7,l2_8,l2_9,l2_10,l2_11,l2_12,l2_13,l2_14,l2_15;
    float hp0,hp1,hp2,hp3,hp4,hp5,hp6,hp7,hp8,hp9,hp10,hp11,hp12,hp13,hp14,hp15;

#define L1_BODY(i) s = fmaf(gW1[(o_) * FIN + i], xi##i, s);
#define L1_O(o) { const int o_ = (o); float s = 0.f; REP8A(L1_BODY) l1_##o = elu_f(s); }
    REP16A(L1_O)
#undef L1_O
#undef L1_BODY
#define L2_BODY(i) s = fmaf(gW2[(o_) * NH + i], l1_##i, s);
#define L2_O(o) { const int o_ = (o); float s = gb2[o_]; REP16B(L2_BODY) l2_##o = elu_f(s); }
    REP16A(L2_O)
#undef L2_O
#undef L2_BODY
#define L3_BODY(i) s = fmaf(gW3[(o_) * NH + i], l2_##i, s);
#define L3_O(o) { const int o_ = (o); float s = gb3[o_]; REP16B(L3_BODY) hp##o = elu_f(s); }
    REP16A(L3_O)
#undef L3_O
#undef L3_BODY

    // ---- base = be + (We_a - We_b) . hp, stash to LDS immediately (frees regs) ----
    {
        float* sb = &sbaseA[w][t & 63][0];
#define BAS_BODY(i) s = fmaf(gWe[(o_) * 32 + i] - gWe[(o_) * 32 + 16 + i], hp##i, s);
#define BAS_O(o) { const int o_ = (o); float s = gbe[o_]; REP16B(BAS_BODY) sb[o_] = s; }
        REP16A(BAS_O)
#undef BAS_O
#undef BAS_BODY
    }

    // ---- B-fragment for edge MFMA: split of We_b = We[:,16:32] (per-lane global float4) ----
    s8v eB1;
    {
        float4 wv = *reinterpret_cast<const float4*>(gWe + lc * 32 + 16 + 4 * lq);
        unsigned h0 = bf16r(wv.x), h1 = bf16r(wv.y), h2 = bf16r(wv.z), h3 = bf16r(wv.w);
        unsigned g0 = bf16r(wv.x - ush2f((unsigned short)h0));
        unsigned g1 = bf16r(wv.y - ush2f((unsigned short)h1));
        unsigned g2 = bf16r(wv.z - ush2f((unsigned short)h2));
        unsigned g3 = bf16r(wv.w - ush2f((unsigned short)h3));
        eB1 = (s8v){(short)h0, (short)h1, (short)h2, (short)h3,
                    (short)g0, (short)g1, (short)g2, (short)g3};
    }

    float sqp = 0.f;
#define SQ_I(i) sqp = fmaf(hp##i, hp##i, sqp);
    REP16A(SQ_I)
#undef SQ_I
    const float sqp2 = 0.5f * sqp;

    // ---- bf16 hi/lo split of hp, store fragment-native ----
#define PACKQ(q, A, B, C, D) { \
    unsigned ha = bf16r(hp##A), hb = bf16r(hp##B), hc = bf16r(hp##C), hd = bf16r(hp##D); \
    float ra = hp##A - ush2f((unsigned short)ha); \
    float rb = hp##B - ush2f((unsigned short)hb); \
    float rc = hp##C - ush2f((unsigned short)hc); \
    float rd = hp##D - ush2f((unsigned short)hd); \
    unsigned la = bf16r(ra), lb = bf16r(rb), lcc = bf16r(rc), ld = bf16r(rd); \
    u4v pk; pk.x = ha | (hb << 16); pk.y = hc | (hd << 16); \
            pk.z = la | (lb << 16); pk.w = lcc | (ld << 16); \
    *(u4v*)&hF[t >> 4][q][(t & 15) * 8] = pk; }
    PACKQ(0, 0, 1, 2, 3)
    PACKQ(1, 4, 5, 6, 7)
    PACKQ(2, 8, 9, 10, 11)
    PACKQ(3, 12, 13, 14, 15)
#undef PACKQ
    sq2arr[t] = sqp2;
    __syncthreads();   // hF / sq2arr valid block-wide

    // ---- kNN: tt-outer distributed select, no LDS panel ----
    KNN_TT(0)
    KNN_TT(1)
    KNN_TT(2)
    KNN_TT(3)

    // ---- edge MLP via MFMA + max-then-ELU + in-register pool ----
    float psum = 0.f;
    {
        const s8v eB2 = __builtin_shufflevector(eB1, eB1, 4, 5, 6, 7, 0, 1, 2, 3);
        const int erow = lc;            // A-row within tile = edge index 0..15
        #pragma unroll 4
        for (int tt = 0; tt < 32; ++tt) {
            uint2 jv = jjarr[w][2 * tt + (erow >> 3)];
            unsigned word = (erow & 4) ? jv.y : jv.x;
            int jp = (int)((word >> ((erow & 3) * 8)) & 0xFFu);
            const s8v av = *(const s8v*)&hF[jp >> 4][lq][(jp & 15) * 8];
            f4v z = {0.f, 0.f, 0.f, 0.f};
            f4v d1 = __builtin_amdgcn_mfma_f32_16x16x32_bf16(av, eB1, z, 0, 0, 0);
            d1     = __builtin_amdgcn_mfma_f32_16x16x32_bf16(av, eB2, d1, 0, 0, 0);
            // lane holds rows 4*lq..4*lq+3 (one particle's 4 k's); pair with lq^1
            float mx = fmaxf(fmaxf(d1[0], d1[1]), fmaxf(d1[2], d1[3]));
            mx = fmaxf(mx, __shfl_xor(mx, 16, 64));
            float bz = sbaseA[w][2 * tt + (lq >> 1)][lc];
            psum += elu_f(mx + bz);     // each (p,col) contributed by exactly 2 lanes
        }
    }
    psum += __shfl_xor(psum, 16, 64);
    psum += __shfl_xor(psum, 32, 64);
    if ((t & 63) < 16) spool[(w << 4) + lc] = psum;   // = 2 * sum_p node[p][lc] over wave
    __syncthreads();

    // ---- head MLP + sigmoid (weights direct from global) ----
    if (t == 0) {
#define PL(i) const float pl##i = (spool[i] + spool[16 + i] + spool[32 + i] + spool[48 + i]) * (1.f / 512.f);
        REP16A(PL)
#undef PL
        float o1_0,o1_1,o1_2,o1_3,o1_4,o1_5,o1_6,o1_7;
#define HD_BODY(i) s = fmaf(gWo1[(o_) * NH + i], pl##i, s);
#define HD_O(o) { const int o_ = (o); float s = gbo1[o_]; REP16B(HD_BODY) o1_##o = elu_f(s); }
        REP8A(HD_O)
#undef HD_O
#undef HD_BODY
        float o2 = gbo2[0];
        o2 = fmaf(gWo2[0], o1_0, o2); o2 = fmaf(gWo2[1], o1_1, o2);
        o2 = fmaf(gWo2[2], o1_2, o2); o2 = fmaf(gWo2[3], o1_3, o2);
        o2 = fmaf(gWo2[4], o1_4, o2); o2 = fmaf(gWo2[5], o1_5, o2);
        o2 = fmaf(gWo2[6], o1_6, o2); o2 = fmaf(gWo2[7], o1_7, o2);
        gout[b] = 1.f / (1.f + expf(-o2));
    }
}

extern "C" void kernel_launch(void* const* d_in, const int* in_sizes, int n_in,
                              void* d_out, int out_size, void* d_ws, size_t ws_size,
                              hipStream_t stream) {
    const float* x   = (const float*)d_in[0];
    const float* W1  = (const float*)d_in[1];
    const float* W2  = (const float*)d_in[2];
    const float* b2  = (const float*)d_in[3];
    const float* W3  = (const float*)d_in[4];
    const float* b3  = (const float*)d_in[5];
    const float* We  = (const float*)d_in[6];
    const float* be  = (const float*)d_in[7];
    const float* Wo1 = (const float*)d_in[8];
    const float* bo1 = (const float*)d_in[9];
    const float* Wo2 = (const float*)d_in[10];
    const float* bo2 = (const float*)d_in[11];
    float* out = (float*)d_out;

    hipLaunchKernelGGL(edgenet_kernel, dim3(NB), dim3(NP), 0, stream,
                       x, W1, W2, b2, W3, b3, We, be, Wo1, bo1, Wo2, bo2, out);
}

// Round 11
// 125.850 us; speedup vs baseline: 4.2622x; 1.0450x over previous
//
#include <hip/hip_runtime.h>
#include <math.h>

#define NB 1024
#define NP 256
#define FIN 8
#define NH 16
#define NK 8

#define REP8A(X)  X(0) X(1) X(2) X(3) X(4) X(5) X(6) X(7)
#define REP16A(X) X(0) X(1) X(2) X(3) X(4) X(5) X(6) X(7) X(8) X(9) X(10) X(11) X(12) X(13) X(14) X(15)
#define REP16B(X) X(0) X(1) X(2) X(3) X(4) X(5) X(6) X(7) X(8) X(9) X(10) X(11) X(12) X(13) X(14) X(15)

typedef short s8v __attribute__((ext_vector_type(8)));
typedef float f4v __attribute__((ext_vector_type(4)));
typedef unsigned int u4v __attribute__((ext_vector_type(4)));

__device__ __forceinline__ float elu_f(float v) {
    return v > 0.f ? v : (__expf(v) - 1.f);
}
__device__ __forceinline__ unsigned bf16r(float f) {   // round-to-nearest-even bf16 bits
    unsigned u = __float_as_uint(f);
    return (u + 0x7FFFu + ((u >> 16) & 1u)) >> 16;
}
__device__ __forceinline__ float ush2f(unsigned short u) {
    return __uint_as_float(((unsigned)u) << 16);
}

// compare-exchange on packed float keys (exact)
#define CE(a, b) { float lo_ = fminf(a, b), hi_ = fmaxf(a, b); a = lo_; b = hi_; }
// Batcher odd-even mergesort, 8 elements, 19 CE
#define SORT8(x0,x1,x2,x3,x4,x5,x6,x7) \
    CE(x0,x1) CE(x2,x3) CE(x4,x5) CE(x6,x7) \
    CE(x0,x2) CE(x1,x3) CE(x4,x6) CE(x5,x7) \
    CE(x1,x2) CE(x5,x6) \
    CE(x0,x4) CE(x1,x5) CE(x2,x6) CE(x3,x7) \
    CE(x2,x4) CE(x3,x5) \
    CE(x1,x2) CE(x3,x4) CE(x5,x6)
// merge sorted-asc x0..x7 into running sorted-asc P##0..P##7, keep lowest 8
#define MERGE8P(P,x0,x1,x2,x3,x4,x5,x6,x7) \
    P##0 = fminf(P##0, x7); P##1 = fminf(P##1, x6); P##2 = fminf(P##2, x5); P##3 = fminf(P##3, x4); \
    P##4 = fminf(P##4, x3); P##5 = fminf(P##5, x2); P##6 = fminf(P##6, x1); P##7 = fminf(P##7, x0); \
    CE(P##0,P##4) CE(P##1,P##5) CE(P##2,P##6) CE(P##3,P##7) \
    CE(P##0,P##2) CE(P##1,P##3) CE(P##4,P##6) CE(P##5,P##7) \
    CE(P##0,P##1) CE(P##2,P##3) CE(P##4,P##5) CE(P##6,P##7)

#define KEYV(val, c) __uint_as_float((__float_as_uint((val) + sqp2) & 0xFFFFFF00u) | (unsigned)(c))

__global__ __attribute__((amdgpu_flat_work_group_size(256, 256),
                          amdgpu_waves_per_eu(2, 4)))
void edgenet_kernel(
    const float* __restrict__ gx,
    const float* __restrict__ gW1, const float* __restrict__ gW2, const float* __restrict__ gb2,
    const float* __restrict__ gW3, const float* __restrict__ gb3,
    const float* __restrict__ gWe, const float* __restrict__ gbe,
    const float* __restrict__ gWo1, const float* __restrict__ gbo1,
    const float* __restrict__ gWo2, const float* __restrict__ gbo2,
    float* __restrict__ gout)
{
    const int b  = blockIdx.x;
    const int t  = threadIdx.x;
    const int w  = t >> 6;          // wave id (0..3)
    const int lq = (t >> 4) & 3;    // lane k-group
    const int lc = t & 15;          // lane row/col-in-tile

    // ---- LDS (~38.1 KB -> 4 blocks/CU) ----
    __shared__ __align__(16) unsigned short hF[16][4][136];
    __shared__ __align__(16) float sq2arr[256];          // 0.5*||h||^2
    __shared__ __align__(16) float sbaseA[4][64][17];    // per-wave base rows
    __shared__ __align__(16) uint2 jjarr[4][64];         // per-wave packed neighbor idx
    __shared__ float spool[64];

    // ---- load particle ----
    float xi0, xi1, xi2, xi3, xi4, xi5, xi6, xi7;
    {
        const float4* xr = reinterpret_cast<const float4*>(gx + (size_t)b * (NP * FIN) + t * FIN);
        float4 v0 = xr[0], v1 = xr[1];
        xi0 = v0.x; xi1 = v0.y; xi2 = v0.z; xi3 = v0.w;
        xi4 = v1.x; xi5 = v1.y; xi6 = v1.z; xi7 = v1.w;
    }

    // ---- encoder MLP 8->16->16->16 (weights direct from global, uniform) ----
    float l1_0,l1_1,l1_2,l1_3,l1_4,l1_5,l1_6,l1_7,l1_8,l1_9,l1_10,l1_11,l1_12,l1_13,l1_14,l1_15;
    float l2_0,l2_1,l2_2,l2_3,l2_4,l2_5,l2_6,l2_7,l2_8,l2_9,l2_10,l2_11,l2_12,l2_13,l2_14,l2_15;
    float hp0,hp1,hp2,hp3,hp4,hp5,hp6,hp7,hp8,hp9,hp10,hp11,hp12,hp13,hp14,hp15;

#define L1_BODY(i) s = fmaf(gW1[(o_) * FIN + i], xi##i, s);
#define L1_O(o) { const int o_ = (o); float s = 0.f; REP8A(L1_BODY) l1_##o = elu_f(s); }
    REP16A(L1_O)
#undef L1_O
#undef L1_BODY
#define L2_BODY(i) s = fmaf(gW2[(o_) * NH + i], l1_##i, s);
#define L2_O(o) { const int o_ = (o); float s = gb2[o_]; REP16B(L2_BODY) l2_##o = elu_f(s); }
    REP16A(L2_O)
#undef L2_O
#undef L2_BODY
#define L3_BODY(i) s = fmaf(gW3[(o_) * NH + i], l2_##i, s);
#define L3_O(o) { const int o_ = (o); float s = gb3[o_]; REP16B(L3_BODY) hp##o = elu_f(s); }
    REP16A(L3_O)
#undef L3_O
#undef L3_BODY

    // ---- base = be + (We_a - We_b) . hp, stash to LDS immediately (frees regs) ----
    {
        float* sb = &sbaseA[w][t & 63][0];
#define BAS_BODY(i) s = fmaf(gWe[(o_) * 32 + i] - gWe[(o_) * 32 + 16 + i], hp##i, s);
#define BAS_O(o) { const int o_ = (o); float s = gbe[o_]; REP16B(BAS_BODY) sb[o_] = s; }
        REP16A(BAS_O)
#undef BAS_O
#undef BAS_BODY
    }

    // ---- B-fragment for edge MFMA: split of We_b = We[:,16:32] (per-lane global float4) ----
    s8v eB1;
    {
        float4 wv = *reinterpret_cast<const float4*>(gWe + lc * 32 + 16 + 4 * lq);
        unsigned h0 = bf16r(wv.x), h1 = bf16r(wv.y), h2 = bf16r(wv.z), h3 = bf16r(wv.w);
        unsigned g0 = bf16r(wv.x - ush2f((unsigned short)h0));
        unsigned g1 = bf16r(wv.y - ush2f((unsigned short)h1));
        unsigned g2 = bf16r(wv.z - ush2f((unsigned short)h2));
        unsigned g3 = bf16r(wv.w - ush2f((unsigned short)h3));
        eB1 = (s8v){(short)h0, (short)h1, (short)h2, (short)h3,
                    (short)g0, (short)g1, (short)g2, (short)g3};
    }

    float sqp = 0.f;
#define SQ_I(i) sqp = fmaf(hp##i, hp##i, sqp);
    REP16A(SQ_I)
#undef SQ_I
    const float sqp2 = 0.5f * sqp;

    // ---- bf16 hi/lo split of hp, store fragment-native ----
#define PACKQ(q, A, B, C, D) { \
    unsigned ha = bf16r(hp##A), hb = bf16r(hp##B), hc = bf16r(hp##C), hd = bf16r(hp##D); \
    float ra = hp##A - ush2f((unsigned short)ha); \
    float rb = hp##B - ush2f((unsigned short)hb); \
    float rc = hp##C - ush2f((unsigned short)hc); \
    float rd = hp##D - ush2f((unsigned short)hd); \
    unsigned la = bf16r(ra), lb = bf16r(rb), lcc = bf16r(rc), ld = bf16r(rd); \
    u4v pk; pk.x = ha | (hb << 16); pk.y = hc | (hd << 16); \
            pk.z = la | (lb << 16); pk.w = lcc | (ld << 16); \
    *(u4v*)&hF[t >> 4][q][(t & 15) * 8] = pk; }
    PACKQ(0, 0, 1, 2, 3)
    PACKQ(1, 4, 5, 6, 7)
    PACKQ(2, 8, 9, 10, 11)
    PACKQ(3, 12, 13, 14, 15)
#undef PACKQ
    sq2arr[t] = sqp2;
    __syncthreads();   // hF / sq2arr valid block-wide

    // ---- negated own fragments (sign-flip is exact for bf16 hi and lo) ----
    // d' = mfma(b2, naf, mfma(b1, naf, C=sq2_cand)) = sq2_cand - h_cand.h_own
#define LDNAF(i) s8v naf##i; { \
    u4v au = __builtin_bit_cast(u4v, *(const s8v*)&hF[4 * w + (i)][lq][lc * 8]); \
    au.x ^= 0x80008000u; au.y ^= 0x80008000u; au.z ^= 0x80008000u; au.w ^= 0x80008000u; \
    naf##i = __builtin_bit_cast(s8v, au); }
    LDNAF(0) LDNAF(1) LDNAF(2) LDNAF(3)
#undef LDNAF

    // ---- kNN: fused jt2-outer loop, 4 own-tiles inside, shared B/sq loads ----
    float Ra0,Ra1,Ra2,Ra3,Ra4,Ra5,Ra6,Ra7;
    float Rb0,Rb1,Rb2,Rb3,Rb4,Rb5,Rb6,Rb7;
    float Rc0,Rc1,Rc2,Rc3,Rc4,Rc5,Rc6,Rc7;
    float Rd0,Rd1,Rd2,Rd3,Rd4,Rd5,Rd6,Rd7;
    {
        const float big = __uint_as_float(0x7F7FFFFFu);
        Ra0=Ra1=Ra2=Ra3=Ra4=Ra5=Ra6=Ra7 = big;
        Rb0=Rb1=Rb2=Rb3=Rb4=Rb5=Rb6=Rb7 = big;
        Rc0=Rc1=Rc2=Rc3=Rc4=Rc5=Rc6=Rc7 = big;
        Rd0=Rd1=Rd2=Rd3=Rd4=Rd5=Rd6=Rd7 = big;
    }

    for (int jt2 = 0; jt2 < 8; ++jt2) {
        const s8v b1a = *(const s8v*)&hF[2 * jt2][lq][lc * 8];
        const s8v b1b = *(const s8v*)&hF[2 * jt2 + 1][lq][lc * 8];
        const s8v b2a = __builtin_shufflevector(b1a, b1a, 4, 5, 6, 7, 0, 1, 2, 3);
        const s8v b2b = __builtin_shufflevector(b1b, b1b, 4, 5, 6, 7, 0, 1, 2, 3);
        const f4v sqa = *(const f4v*)&sq2arr[32 * jt2 + 4 * lq];
        const f4v sqb = *(const f4v*)&sq2arr[32 * jt2 + 16 + 4 * lq];
        const int c0 = 32 * jt2 + 4 * lq, c1 = c0 + 16;

#define GTT(naf, P) { \
        f4v da = __builtin_amdgcn_mfma_f32_16x16x32_bf16(b1a, naf, sqa, 0, 0, 0); \
        da     = __builtin_amdgcn_mfma_f32_16x16x32_bf16(b2a, naf, da,  0, 0, 0); \
        f4v db = __builtin_amdgcn_mfma_f32_16x16x32_bf16(b1b, naf, sqb, 0, 0, 0); \
        db     = __builtin_amdgcn_mfma_f32_16x16x32_bf16(b2b, naf, db,  0, 0, 0); \
        float k0 = KEYV(da[0], c0 + 0), k1 = KEYV(da[1], c0 + 1); \
        float k2 = KEYV(da[2], c0 + 2), k3 = KEYV(da[3], c0 + 3); \
        float k4 = KEYV(db[0], c1 + 0), k5 = KEYV(db[1], c1 + 1); \
        float k6 = KEYV(db[2], c1 + 2), k7 = KEYV(db[3], c1 + 3); \
        SORT8(k0, k1, k2, k3, k4, k5, k6, k7) \
        MERGE8P(P, k0, k1, k2, k3, k4, k5, k6, k7) }
        GTT(naf0, Ra)
        GTT(naf1, Rb)
        GTT(naf2, Rc)
        GTT(naf3, Rd)
#undef GTT
    }

    // ---- converge 4 lq-lanes per own-tile; owner lane writes packed indices ----
#define FIN_TT(P, ttc) { \
    { float o0 = __shfl_xor(P##0, 16), o1 = __shfl_xor(P##1, 16), \
            o2 = __shfl_xor(P##2, 16), o3 = __shfl_xor(P##3, 16), \
            o4 = __shfl_xor(P##4, 16), o5 = __shfl_xor(P##5, 16), \
            o6 = __shfl_xor(P##6, 16), o7 = __shfl_xor(P##7, 16); \
      MERGE8P(P, o0, o1, o2, o3, o4, o5, o6, o7) } \
    { float o0 = __shfl_xor(P##0, 32), o1 = __shfl_xor(P##1, 32), \
            o2 = __shfl_xor(P##2, 32), o3 = __shfl_xor(P##3, 32), \
            o4 = __shfl_xor(P##4, 32), o5 = __shfl_xor(P##5, 32), \
            o6 = __shfl_xor(P##6, 32), o7 = __shfl_xor(P##7, 32); \
      MERGE8P(P, o0, o1, o2, o3, o4, o5, o6, o7) } \
    if (lq == (ttc)) { \
        unsigned plo = (__float_as_uint(P##0) & 0xFFu) \
                     | ((__float_as_uint(P##1) & 0xFFu) << 8) \
                     | ((__float_as_uint(P##2) & 0xFFu) << 16) \
                     | ((__float_as_uint(P##3) & 0xFFu) << 24); \
        unsigned phi = (__float_as_uint(P##4) & 0xFFu) \
                     | ((__float_as_uint(P##5) & 0xFFu) << 8) \
                     | ((__float_as_uint(P##6) & 0xFFu) << 16) \
                     | ((__float_as_uint(P##7) & 0xFFu) << 24); \
        jjarr[w][16 * (ttc) + lc] = make_uint2(plo, phi); \
    } }
    FIN_TT(Ra, 0)
    FIN_TT(Rb, 1)
    FIN_TT(Rc, 2)
    FIN_TT(Rd, 3)
#undef FIN_TT

    // ---- edge MLP via MFMA + max-then-ELU + in-register pool ----
    float psum = 0.f;
    {
        const s8v eB2 = __builtin_shufflevector(eB1, eB1, 4, 5, 6, 7, 0, 1, 2, 3);
        const int erow = lc;            // A-row within tile = edge index 0..15
        #pragma unroll 4
        for (int tt = 0; tt < 32; ++tt) {
            uint2 jv = jjarr[w][2 * tt + (erow >> 3)];
            unsigned word = (erow & 4) ? jv.y : jv.x;
            int jp = (int)((word >> ((erow & 3) * 8)) & 0xFFu);
            const s8v av = *(const s8v*)&hF[jp >> 4][lq][(jp & 15) * 8];
            f4v z = {0.f, 0.f, 0.f, 0.f};
            f4v d1 = __builtin_amdgcn_mfma_f32_16x16x32_bf16(av, eB1, z, 0, 0, 0);
            d1     = __builtin_amdgcn_mfma_f32_16x16x32_bf16(av, eB2, d1, 0, 0, 0);
            // lane holds rows 4*lq..4*lq+3 (one particle's 4 k's); pair with lq^1
            float mx = fmaxf(fmaxf(d1[0], d1[1]), fmaxf(d1[2], d1[3]));
            mx = fmaxf(mx, __shfl_xor(mx, 16, 64));
            float bz = sbaseA[w][2 * tt + (lq >> 1)][lc];
            psum += elu_f(mx + bz);     // each (p,col) contributed by exactly 2 lanes
        }
    }
    psum += __shfl_xor(psum, 16, 64);
    psum += __shfl_xor(psum, 32, 64);
    if ((t & 63) < 16) spool[(w << 4) + lc] = psum;   // = 2 * sum_p node[p][lc] over wave
    __syncthreads();

    // ---- head MLP + sigmoid (weights direct from global) ----
    if (t == 0) {
#define PL(i) const float pl##i = (spool[i] + spool[16 + i] + spool[32 + i] + spool[48 + i]) * (1.f / 512.f);
        REP16A(PL)
#undef PL
        float o1_0,o1_1,o1_2,o1_3,o1_4,o1_5,o1_6,o1_7;
#define HD_BODY(i) s = fmaf(gWo1[(o_) * NH + i], pl##i, s);
#define HD_O(o) { const int o_ = (o); float s = gbo1[o_]; REP16B(HD_BODY) o1_##o = elu_f(s); }
        REP8A(HD_O)
#undef HD_O
#undef HD_BODY
        float o2 = gbo2[0];
        o2 = fmaf(gWo2[0], o1_0, o2); o2 = fmaf(gWo2[1], o1_1, o2);
        o2 = fmaf(gWo2[2], o1_2, o2); o2 = fmaf(gWo2[3], o1_3, o2);
        o2 = fmaf(gWo2[4], o1_4, o2); o2 = fmaf(gWo2[5], o1_5, o2);
        o2 = fmaf(gWo2[6], o1_6, o2); o2 = fmaf(gWo2[7], o1_7, o2);
        gout[b] = 1.f / (1.f + expf(-o2));
    }
}

extern "C" void kernel_launch(void* const* d_in, const int* in_sizes, int n_in,
                              void* d_out, int out_size, void* d_ws, size_t ws_size,
                              hipStream_t stream) {
    const float* x   = (const float*)d_in[0];
    const float* W1  = (const float*)d_in[1];
    const float* W2  = (const float*)d_in[2];
    const float* b2  = (const float*)d_in[3];
    const float* W3  = (const float*)d_in[4];
    const float* b3  = (const float*)d_in[5];
    const float* We  = (const float*)d_in[6];
    const float* be  = (const float*)d_in[7];
    const float* Wo1 = (const float*)d_in[8];
    const float* bo1 = (const float*)d_in[9];
    const float* Wo2 = (const float*)d_in[10];
    const float* bo2 = (const float*)d_in[11];
    float* out = (float*)d_out;

    hipLaunchKernelGGL(edgenet_kernel, dim3(NB), dim3(NP), 0, stream,
                       x, W1, W2, b2, W3, b3, We, be, Wo1, bo1, Wo2, bo2, out);
}

// Round 13
// 119.418 us; speedup vs baseline: 4.4917x; 1.0539x over previous
//
#include <hip/hip_runtime.h>
#include <math.h>

#define NB 1024
#define NP 256
#define FIN 8
#define NH 16
#define NK 8

#define REP8A(X)  X(0) X(1) X(2) X(3) X(4) X(5) X(6) X(7)
#define REP16A(X) X(0) X(1) X(2) X(3) X(4) X(5) X(6) X(7) X(8) X(9) X(10) X(11) X(12) X(13) X(14) X(15)
#define REP16B(X) X(0) X(1) X(2) X(3) X(4) X(5) X(6) X(7) X(8) X(9) X(10) X(11) X(12) X(13) X(14) X(15)

typedef short s8v __attribute__((ext_vector_type(8)));
typedef float f4v __attribute__((ext_vector_type(4)));
typedef unsigned int u4v __attribute__((ext_vector_type(4)));

__device__ __forceinline__ float elu_f(float v) {
    return v > 0.f ? v : (__expf(v) - 1.f);
}
__device__ __forceinline__ unsigned bf16r(float f) {   // round-to-nearest-even bf16 bits
    unsigned u = __float_as_uint(f);
    return (u + 0x7FFFu + ((u >> 16) & 1u)) >> 16;
}
__device__ __forceinline__ float ush2f(unsigned short u) {
    return __uint_as_float(((unsigned)u) << 16);
}
// split 4 fp32 into fragment chunk [hi0..hi3 | lo0..lo3] (bf16 hi/lo split)
__device__ __forceinline__ s8v split4(float4 wv) {
    unsigned h0 = bf16r(wv.x), h1 = bf16r(wv.y), h2 = bf16r(wv.z), h3 = bf16r(wv.w);
    unsigned g0 = bf16r(wv.x - ush2f((unsigned short)h0));
    unsigned g1 = bf16r(wv.y - ush2f((unsigned short)h1));
    unsigned g2 = bf16r(wv.z - ush2f((unsigned short)h2));
    unsigned g3 = bf16r(wv.w - ush2f((unsigned short)h3));
    u4v pk; pk.x = h0 | (h1 << 16); pk.y = h2 | (h3 << 16);
            pk.z = g0 | (g1 << 16); pk.w = g2 | (g3 << 16);
    return __builtin_bit_cast(s8v, pk);
}
#define HSWAP(v) __builtin_shufflevector(v, v, 4, 5, 6, 7, 0, 1, 2, 3)
#define MFMA16(A, B, C) __builtin_amdgcn_mfma_f32_16x16x32_bf16(A, B, C, 0, 0, 0)

// compare-exchange on packed float keys (exact)
#define CE(a, b) { float lo_ = fminf(a, b), hi_ = fmaxf(a, b); a = lo_; b = hi_; }
// Batcher odd-even mergesort, 8 elements, 19 CE
#define SORT8(x0,x1,x2,x3,x4,x5,x6,x7) \
    CE(x0,x1) CE(x2,x3) CE(x4,x5) CE(x6,x7) \
    CE(x0,x2) CE(x1,x3) CE(x4,x6) CE(x5,x7) \
    CE(x1,x2) CE(x5,x6) \
    CE(x0,x4) CE(x1,x5) CE(x2,x6) CE(x3,x7) \
    CE(x2,x4) CE(x3,x5) \
    CE(x1,x2) CE(x3,x4) CE(x5,x6)
// merge sorted-asc x0..x7 into running sorted-asc P##0..P##7, keep lowest 8
#define MERGE8P(P,x0,x1,x2,x3,x4,x5,x6,x7) \
    P##0 = fminf(P##0, x7); P##1 = fminf(P##1, x6); P##2 = fminf(P##2, x5); P##3 = fminf(P##3, x4); \
    P##4 = fminf(P##4, x3); P##5 = fminf(P##5, x2); P##6 = fminf(P##6, x1); P##7 = fminf(P##7, x0); \
    CE(P##0,P##4) CE(P##1,P##5) CE(P##2,P##6) CE(P##3,P##7) \
    CE(P##0,P##2) CE(P##1,P##3) CE(P##4,P##6) CE(P##5,P##7) \
    CE(P##0,P##1) CE(P##2,P##3) CE(P##4,P##5) CE(P##6,P##7)

// key: truncated-mantissa distance-surrogate | 8-bit index. No per-particle
// shift: constant offsets never change a top-k set, and zero is consistent
// across the 4 merging lq-lanes (fixes R10/R11's cross-lane shift skew).
#define KEYV(val, c) __uint_as_float((__float_as_uint(val) & 0xFFFFFF00u) | (unsigned)(c))

__global__ __attribute__((amdgpu_flat_work_group_size(256, 256),
                          amdgpu_waves_per_eu(2, 4)))
void edgenet_kernel(
    const float* __restrict__ gx,
    const float* __restrict__ gW1, const float* __restrict__ gW2, const float* __restrict__ gb2,
    const float* __restrict__ gW3, const float* __restrict__ gb3,
    const float* __restrict__ gWe, const float* __restrict__ gbe,
    const float* __restrict__ gWo1, const float* __restrict__ gbo1,
    const float* __restrict__ gWo2, const float* __restrict__ gbo2,
    float* __restrict__ gout)
{
    const int b  = blockIdx.x;
    const int t  = threadIdx.x;
    const int w  = t >> 6;          // wave id (0..3)
    const int lq = (t >> 4) & 3;    // lane k-group
    const int lc = t & 15;          // lane row/col-in-tile

    // ---- LDS (~38.1 KB -> 4 blocks/CU) ----
    __shared__ __align__(16) unsigned short hF[16][4][136];
    __shared__ __align__(16) float sq2arr[256];          // 0.5*||h||^2
    __shared__ __align__(16) float sbaseA[4][64][17];    // per-wave base rows
    __shared__ __align__(16) uint2 jjarr[4][64];         // per-wave packed neighbor idx
    __shared__ float spool[64];

    const f4v zf4 = {0.f, 0.f, 0.f, 0.f};
    const s8v zv8 = (s8v){0, 0, 0, 0, 0, 0, 0, 0};

    // ---- encoder weight fragments: A-operand rows = out-feature lc ----
    s8v w1a = zv8;
    if (lq < 2) w1a = split4(*reinterpret_cast<const float4*>(gW1 + lc * FIN + 4 * lq));
    const s8v w1as = HSWAP(w1a);
    const s8v w2a  = split4(*reinterpret_cast<const float4*>(gW2 + lc * NH + 4 * lq));
    const s8v w2as = HSWAP(w2a);
    const s8v w3a  = split4(*reinterpret_cast<const float4*>(gW3 + lc * NH + 4 * lq));
    const s8v w3as = HSWAP(w3a);
    // biases b2/b3 as C-operands: C[m=4lq+r][*] = b[4lq+r]
    f4v cb2, cb3;
    {
        float4 v2 = *reinterpret_cast<const float4*>(gb2 + 4 * lq);
        float4 v3 = *reinterpret_cast<const float4*>(gb3 + 4 * lq);
        cb2 = (f4v){v2.x, v2.y, v2.z, v2.w};
        cb3 = (f4v){v3.x, v3.y, v3.z, v3.w};
    }

    // ---- encoder via MFMA, fragment-chained; produces hF, sq2arr, naf0..3 ----
    s8v naf0, naf1, naf2, naf3;
#define ENC_TILE(tt, NAF) { \
    s8v xB = zv8; \
    if (lq < 2) { \
        float4 xv = *reinterpret_cast<const float4*>( \
            gx + (size_t)b * (NP * FIN) + (64 * w + 16 * (tt) + lc) * FIN + 4 * lq); \
        xB = split4(xv); } \
    f4v d1 = MFMA16(w1a, xB, zf4); d1 = MFMA16(w1as, xB, d1); \
    s8v hB1 = split4(make_float4(elu_f(d1[0]), elu_f(d1[1]), elu_f(d1[2]), elu_f(d1[3]))); \
    f4v d2 = MFMA16(w2a, hB1, cb2); d2 = MFMA16(w2as, hB1, d2); \
    s8v hB2 = split4(make_float4(elu_f(d2[0]), elu_f(d2[1]), elu_f(d2[2]), elu_f(d2[3]))); \
    f4v d3 = MFMA16(w3a, hB2, cb3); d3 = MFMA16(w3as, hB2, d3); \
    float h0_ = elu_f(d3[0]), h1_ = elu_f(d3[1]), h2_ = elu_f(d3[2]), h3_ = elu_f(d3[3]); \
    s8v hB3 = split4(make_float4(h0_, h1_, h2_, h3_)); \
    *(u4v*)&hF[4 * w + (tt)][lq][lc * 8] = __builtin_bit_cast(u4v, hB3); \
    float sq_ = h0_ * h0_; sq_ = fmaf(h1_, h1_, sq_); \
    sq_ = fmaf(h2_, h2_, sq_); sq_ = fmaf(h3_, h3_, sq_); \
    sq_ += __shfl_xor(sq_, 16, 64); sq_ += __shfl_xor(sq_, 32, 64); \
    if (lq == 0) sq2arr[64 * w + 16 * (tt) + lc] = 0.5f * sq_; \
    { u4v nu = __builtin_bit_cast(u4v, hB3); \
      nu.x ^= 0x80008000u; nu.y ^= 0x80008000u; nu.z ^= 0x80008000u; nu.w ^= 0x80008000u; \
      NAF = __builtin_bit_cast(s8v, nu); } }
    ENC_TILE(0, naf0)
    ENC_TILE(1, naf1)
    ENC_TILE(2, naf2)
    ENC_TILE(3, naf3)
#undef ENC_TILE
    __syncthreads();   // hF / sq2arr valid block-wide

    // ---- kNN: fused jt2-outer loop, 4 own-tiles inside, shared B/sq loads ----
    float Ra0,Ra1,Ra2,Ra3,Ra4,Ra5,Ra6,Ra7;
    float Rb0,Rb1,Rb2,Rb3,Rb4,Rb5,Rb6,Rb7;
    float Rc0,Rc1,Rc2,Rc3,Rc4,Rc5,Rc6,Rc7;
    float Rd0,Rd1,Rd2,Rd3,Rd4,Rd5,Rd6,Rd7;
    {
        const float big = __uint_as_float(0x7F7FFFFFu);
        Ra0=Ra1=Ra2=Ra3=Ra4=Ra5=Ra6=Ra7 = big;
        Rb0=Rb1=Rb2=Rb3=Rb4=Rb5=Rb6=Rb7 = big;
        Rc0=Rc1=Rc2=Rc3=Rc4=Rc5=Rc6=Rc7 = big;
        Rd0=Rd1=Rd2=Rd3=Rd4=Rd5=Rd6=Rd7 = big;
    }

    for (int jt2 = 0; jt2 < 8; ++jt2) {
        const s8v b1a = *(const s8v*)&hF[2 * jt2][lq][lc * 8];
        const s8v b1b = *(const s8v*)&hF[2 * jt2 + 1][lq][lc * 8];
        const s8v b2a = HSWAP(b1a);
        const s8v b2b = HSWAP(b1b);
        const f4v sqa = *(const f4v*)&sq2arr[32 * jt2 + 4 * lq];
        const f4v sqb = *(const f4v*)&sq2arr[32 * jt2 + 16 + 4 * lq];
        const int c0 = 32 * jt2 + 4 * lq, c1 = c0 + 16;

#define GTT(naf, P) { \
        f4v da = MFMA16(b1a, naf, sqa); da = MFMA16(b2a, naf, da); \
        f4v db = MFMA16(b1b, naf, sqb); db = MFMA16(b2b, naf, db); \
        float k0 = KEYV(da[0], c0 + 0), k1 = KEYV(da[1], c0 + 1); \
        float k2 = KEYV(da[2], c0 + 2), k3 = KEYV(da[3], c0 + 3); \
        float k4 = KEYV(db[0], c1 + 0), k5 = KEYV(db[1], c1 + 1); \
        float k6 = KEYV(db[2], c1 + 2), k7 = KEYV(db[3], c1 + 3); \
        SORT8(k0, k1, k2, k3, k4, k5, k6, k7) \
        MERGE8P(P, k0, k1, k2, k3, k4, k5, k6, k7) }
        GTT(naf0, Ra)
        GTT(naf1, Rb)
        GTT(naf2, Rc)
        GTT(naf3, Rd)
#undef GTT
    }

    // ---- converge 4 lq-lanes per own-tile; owner lane writes packed indices ----
#define FIN_TT(P, ttc) { \
    { float o0 = __shfl_xor(P##0, 16), o1 = __shfl_xor(P##1, 16), \
            o2 = __shfl_xor(P##2, 16), o3 = __shfl_xor(P##3, 16), \
            o4 = __shfl_xor(P##4, 16), o5 = __shfl_xor(P##5, 16), \
            o6 = __shfl_xor(P##6, 16), o7 = __shfl_xor(P##7, 16); \
      MERGE8P(P, o0, o1, o2, o3, o4, o5, o6, o7) } \
    { float o0 = __shfl_xor(P##0, 32), o1 = __shfl_xor(P##1, 32), \
            o2 = __shfl_xor(P##2, 32), o3 = __shfl_xor(P##3, 32), \
            o4 = __shfl_xor(P##4, 32), o5 = __shfl_xor(P##5, 32), \
            o6 = __shfl_xor(P##6, 32), o7 = __shfl_xor(P##7, 32); \
      MERGE8P(P, o0, o1, o2, o3, o4, o5, o6, o7) } \
    if (lq == (ttc)) { \
        unsigned plo = (__float_as_uint(P##0) & 0xFFu) \
                     | ((__float_as_uint(P##1) & 0xFFu) << 8) \
                     | ((__float_as_uint(P##2) & 0xFFu) << 16) \
                     | ((__float_as_uint(P##3) & 0xFFu) << 24); \
        unsigned phi = (__float_as_uint(P##4) & 0xFFu) \
                     | ((__float_as_uint(P##5) & 0xFFu) << 8) \
                     | ((__float_as_uint(P##6) & 0xFFu) << 16) \
                     | ((__float_as_uint(P##7) & 0xFFu) << 24); \
        jjarr[w][16 * (ttc) + lc] = make_uint2(plo, phi); \
    } }
    FIN_TT(Ra, 0)
    FIN_TT(Rb, 1)
    FIN_TT(Rc, 2)
    FIN_TT(Rd, 3)
#undef FIN_TT

    // ---- base = be + We_c . h via MFMA (post-select: keeps select live-set lean) ----
    {
        float4 wa = *reinterpret_cast<const float4*>(gWe + lc * 32 + 4 * lq);
        float4 wc = *reinterpret_cast<const float4*>(gWe + lc * 32 + 16 + 4 * lq);
        const s8v wca  = split4(make_float4(wa.x - wc.x, wa.y - wc.y, wa.z - wc.z, wa.w - wc.w));
        const s8v wcas = HSWAP(wca);
        float4 bev = *reinterpret_cast<const float4*>(gbe + 4 * lq);
        const f4v cbe = (f4v){bev.x, bev.y, bev.z, bev.w};
#define BASE_TILE(NAF, tt) { \
        u4v pu = __builtin_bit_cast(u4v, NAF); \
        pu.x ^= 0x80008000u; pu.y ^= 0x80008000u; pu.z ^= 0x80008000u; pu.w ^= 0x80008000u; \
        s8v hB = __builtin_bit_cast(s8v, pu); \
        f4v bd = MFMA16(wca, hB, cbe); bd = MFMA16(wcas, hB, bd); \
        float* sb = &sbaseA[w][16 * (tt) + lc][4 * lq]; \
        sb[0] = bd[0]; sb[1] = bd[1]; sb[2] = bd[2]; sb[3] = bd[3]; }
        BASE_TILE(naf0, 0)
        BASE_TILE(naf1, 1)
        BASE_TILE(naf2, 2)
        BASE_TILE(naf3, 3)
#undef BASE_TILE
    }

    // ---- edge MLP via MFMA + max-then-ELU + in-register pool ----
    float psum = 0.f;
    {
        // B-fragment: split of We_b = We[:,16:32]
        float4 wv = *reinterpret_cast<const float4*>(gWe + lc * 32 + 16 + 4 * lq);
        const s8v eB1 = split4(wv);
        const s8v eB2 = HSWAP(eB1);
        const int erow = lc;            // A-row within tile = edge index 0..15
        #pragma unroll 4
        for (int tt = 0; tt < 32; ++tt) {
            uint2 jv = jjarr[w][2 * tt + (erow >> 3)];
            unsigned word = (erow & 4) ? jv.y : jv.x;
            int jp = (int)((word >> ((erow & 3) * 8)) & 0xFFu);
            const s8v av = *(const s8v*)&hF[jp >> 4][lq][(jp & 15) * 8];
            f4v d1 = MFMA16(av, eB1, zf4);
            d1     = MFMA16(av, eB2, d1);
            // lane holds rows 4*lq..4*lq+3 (one particle's 4 k's); pair with lq^1
            float mx = fmaxf(fmaxf(d1[0], d1[1]), fmaxf(d1[2], d1[3]));
            mx = fmaxf(mx, __shfl_xor(mx, 16, 64));
            float bz = sbaseA[w][2 * tt + (lq >> 1)][lc];
            psum += elu_f(mx + bz);     // each (p,col) contributed by exactly 2 lanes
        }
    }
    psum += __shfl_xor(psum, 16, 64);
    psum += __shfl_xor(psum, 32, 64);
    if ((t & 63) < 16) spool[(w << 4) + lc] = psum;   // = 2 * sum_p node[p][lc] over wave
    __syncthreads();

    // ---- head MLP + sigmoid (weights direct from global) ----
    if (t == 0) {
#define PL(i) const float pl##i = (spool[i] + spool[16 + i] + spool[32 + i] + spool[48 + i]) * (1.f / 512.f);
        REP16A(PL)
#undef PL
        float o1_0,o1_1,o1_2,o1_3,o1_4,o1_5,o1_6,o1_7;
#define HD_BODY(i) s = fmaf(gWo1[(o_) * NH + i], pl##i, s);
#define HD_O(o) { const int o_ = (o); float s = gbo1[o_]; REP16B(HD_BODY) o1_##o = elu_f(s); }
        REP8A(HD_O)
#undef HD_O
#undef HD_BODY
        float o2 = gbo2[0];
        o2 = fmaf(gWo2[0], o1_0, o2); o2 = fmaf(gWo2[1], o1_1, o2);
        o2 = fmaf(gWo2[2], o1_2, o2); o2 = fmaf(gWo2[3], o1_3, o2);
        o2 = fmaf(gWo2[4], o1_4, o2); o2 = fmaf(gWo2[5], o1_5, o2);
        o2 = fmaf(gWo2[6], o1_6, o2); o2 = fmaf(gWo2[7], o1_7, o2);
        gout[b] = 1.f / (1.f + expf(-o2));
    }
}

extern "C" void kernel_launch(void* const* d_in, const int* in_sizes, int n_in,
                              void* d_out, int out_size, void* d_ws, size_t ws_size,
                              hipStream_t stream) {
    const float* x   = (const float*)d_in[0];
    const float* W1  = (const float*)d_in[1];
    const float* W2  = (const float*)d_in[2];
    const float* b2  = (const float*)d_in[3];
    const float* W3  = (const float*)d_in[4];
    const float* b3  = (const float*)d_in[5];
    const float* We  = (const float*)d_in[6];
    const float* be  = (const float*)d_in[7];
    const float* Wo1 = (const float*)d_in[8];
    const float* bo1 = (const float*)d_in[9];
    const float* Wo2 = (const float*)d_in[10];
    const float* bo2 = (const float*)d_in[11];
    float* out = (float*)d_out;

    hipLaunchKernelGGL(edgenet_kernel, dim3(NB), dim3(NP), 0, stream,
                       x, W1, W2, b2, W3, b3, We, be, Wo1, bo1, Wo2, bo2, out);
}